// Round 3
// baseline (273.883 us; speedup 1.0000x reference)
//
#include <hip/hip_runtime.h>
#include <hip/hip_bf16.h>

#define NB 4096

// workspace layout (bytes, 16B-aligned)
#define XT_OFF  0u           // 784*4096*4      = 12,845,056
#define H1_OFF  12845056u    // 16*169*4096*4   = 44,302,336
#define H2_OFF  57147392u    // 800*4096*4      = 13,107,200
#define W2R_OFF 70254592u    // 25*16*32*48*4   =  2,457,600
// end 72,712,192

// ---------------------------------------------------------------------------
// fused prep: blocks [0,3200) transpose x -> xT; blocks [3200,5600) gather w2
// w2r layout: [pos25][c16][o32][cv4][12pad]
__global__ __launch_bounds__(256) void k_prep(const float* __restrict__ x,
                                              const float* __restrict__ w2,
                                              float* __restrict__ xT,
                                              float* __restrict__ w2r) {
  const int bx = blockIdx.x;
  if (bx < 3200) {
    __shared__ float t[32][33];
    const int c0 = (bx % 25) * 32;
    const int n0 = (bx / 25) * 32;
    const int tx = threadIdx.x & 31, ty = threadIdx.x >> 5;
    #pragma unroll
    for (int i = 0; i < 32; i += 8) {
      const int c = c0 + tx;
      if (c < 784) t[ty + i][tx] = x[(n0 + ty + i) * 784 + c];
    }
    __syncthreads();
    #pragma unroll
    for (int i = 0; i < 32; i += 8) {
      const int c = c0 + ty + i;
      if (c < 784) xT[c * NB + n0 + tx] = t[tx][ty + i];
    }
  } else {
    const int idx = (bx - 3200) * 256 + threadIdx.x;  // 614,400 elems
    const int pos = idx / 24576;
    const int r1 = idx % 24576;
    const int c = r1 / 1536;
    const int r2 = r1 % 1536;
    const int o = r2 / 48;
    const int t = r2 % 48;
    const int cv = t / 12, k = t % 12;
    float v = 0.f;
    if (k < 9) {
      const int i = pos / 5, j = pos % 5;
      const int y = 2 * i + (cv >> 1), xx = 2 * j + (cv & 1);
      v = w2[((o * 16 + c) * 9 + k) * 121 + y * 11 + xx];
    }
    w2r[idx] = v;
  }
}

// ---------------------------------------------------------------------------
// LC1 + ReLU + pool.  xT (784,N) -> h1 (16,13,13,N)
// block 256 = 4 og (4 o, wave-uniform) x 64 nl (4 n); grid (16 nt, 169 pos)
__global__ __launch_bounds__(256, 3) void k_lc1(const float* __restrict__ xT,
                                                const float* __restrict__ w1,
                                                const float* __restrict__ b1,
                                                float* __restrict__ h1) {
  __shared__ __align__(16) float sw[640];  // [o16][36] + bias [o][conv] at 576
  const int pos = blockIdx.y;
  const int i = pos / 13, j = pos % 13;
  const int tid = threadIdx.x;
  const int og = tid >> 6, nl = tid & 63;
  const int o0 = og * 4;
  const int n = blockIdx.x * 256 + nl * 4;

  for (int idx = tid; idx < 640; idx += 256) {
    float v;
    if (idx < 576) {
      const int o = idx / 36, t = idx % 36;
      const int cv = t / 9, k = t % 9;
      const int y = 2 * i + (cv >> 1), xx = 2 * j + (cv & 1);
      v = w1[(o * 9 + k) * 676 + y * 26 + xx];
    } else {
      const int r = idx - 576;
      const int o = r >> 2, cv = r & 3;
      v = b1[(o * 26 + 2 * i + (cv >> 1)) * 26 + 2 * j + (cv & 1)];
    }
    sw[idx] = v;
  }
  __syncthreads();

  float p[16][4];
  #pragma unroll
  for (int r = 0; r < 4; r++)
    #pragma unroll
    for (int cc = 0; cc < 4; cc++) {
      const float4 v = *reinterpret_cast<const float4*>(
          &xT[((2 * i + r) * 28 + (2 * j + cc)) * NB + n]);
      p[r * 4 + cc][0] = v.x; p[r * 4 + cc][1] = v.y;
      p[r * 4 + cc][2] = v.z; p[r * 4 + cc][3] = v.w;
    }

  #pragma unroll
  for (int ot = 0; ot < 4; ot++) {
    const int o = o0 + ot;
    float wf[36];
    const float4* wp = reinterpret_cast<const float4*>(&sw[o * 36]);
    #pragma unroll
    for (int q = 0; q < 9; q++) {
      const float4 v = wp[q];
      wf[4 * q] = v.x; wf[4 * q + 1] = v.y;
      wf[4 * q + 2] = v.z; wf[4 * q + 3] = v.w;
    }
    float s[4][4];
    #pragma unroll
    for (int cv = 0; cv < 4; cv++)
      #pragma unroll
      for (int e = 0; e < 4; e++) s[cv][e] = 0.f;
    #pragma unroll
    for (int cv = 0; cv < 4; cv++) {
      const int dy = cv >> 1, dx = cv & 1;
      #pragma unroll
      for (int k = 0; k < 9; k++) {
        const float wv = wf[cv * 9 + k];
        #pragma unroll
        for (int e = 0; e < 4; e++)
          s[cv][e] += wv * p[(dy + k / 3) * 4 + (dx + k % 3)][e];
      }
    }
    float rr[4];
    #pragma unroll
    for (int e = 0; e < 4; e++) {
      float best = -1e30f;
      #pragma unroll
      for (int cv = 0; cv < 4; cv++)
        best = fmaxf(best, s[cv][e] + sw[576 + o * 4 + cv]);
      rr[e] = fmaxf(best, 0.f);
    }
    float4 res; res.x = rr[0]; res.y = rr[1]; res.z = rr[2]; res.w = rr[3];
    *reinterpret_cast<float4*>(&h1[((o * 13 + i) * 13 + j) * NB + n]) = res;
  }
}

// ---------------------------------------------------------------------------
// LC2 + ReLU + pool.  h1 (16,169,N) -> h2 (800,N)
// block 128 = 8 og (4 o) x 16 nl (4 n); grid (64 nt, 25 pos), nt fastest.
// Patches AND weights LDS-staged, double-buffered: prefetch c+1 at iter top,
// commit to LDS at iter bottom -> HBM latency overlaps the FMA body, and
// og-redundant L1 traffic collapses 8x.
__global__ __launch_bounds__(128) void k_lc2(const float* __restrict__ h1,
                                             const float* __restrict__ w2r,
                                             const float* __restrict__ b2,
                                             float* __restrict__ h2) {
  __shared__ __align__(16) float pb[2][16 * 64];  // patches [pos16][n64], 4KB ea
  __shared__ __align__(16) float wb[2][1536];     // weights [o32][cv4][12], 6KB ea
  const int pos = blockIdx.y;
  const int i = pos / 5, j = pos % 5;
  const int tid = threadIdx.x;
  const int og = tid >> 4;   // 0..7
  const int nl = tid & 15;
  const int o0 = og * 4;
  const int n0 = blockIdx.x * 64;
  const float* wsrc = w2r + pos * 24576;

  // stage c = 0
  #pragma unroll
  for (int r = 0; r < 2; r++) {
    const int idx = tid + 128 * r;
    const int pp = idx >> 4, q = idx & 15;
    *reinterpret_cast<float4*>(&pb[0][idx * 4]) =
        *reinterpret_cast<const float4*>(
            &h1[((2 * i + (pp >> 2)) * 13 + (2 * j + (pp & 3))) * NB + n0 + q * 4]);
  }
  #pragma unroll
  for (int r = 0; r < 3; r++) {
    const int idx = tid + 128 * r;
    *reinterpret_cast<float4*>(&wb[0][idx * 4]) =
        *reinterpret_cast<const float4*>(&wsrc[idx * 4]);
  }
  __syncthreads();

  float acc[4][4][4];  // [ot][cv][e]
  #pragma unroll
  for (int ot = 0; ot < 4; ot++)
    #pragma unroll
    for (int cv = 0; cv < 4; cv++)
      #pragma unroll
      for (int e = 0; e < 4; e++) acc[ot][cv][e] = 0.f;

  for (int c = 0; c < 16; c++) {
    const int b = c & 1;
    float4 ppre[2], wpre[3];
    if (c < 15) {
      #pragma unroll
      for (int r = 0; r < 2; r++) {
        const int idx = tid + 128 * r;
        const int pp = idx >> 4, q = idx & 15;
        ppre[r] = *reinterpret_cast<const float4*>(
            &h1[((c + 1) * 169 + (2 * i + (pp >> 2)) * 13 + (2 * j + (pp & 3))) * NB +
                n0 + q * 4]);
      }
      #pragma unroll
      for (int r = 0; r < 3; r++)
        wpre[r] = *reinterpret_cast<const float4*>(
            &wsrc[(c + 1) * 1536 + (tid + 128 * r) * 4]);
    }
    // patches from LDS (2-way og broadcast within wave: free)
    float p[16][4];
    #pragma unroll
    for (int pp = 0; pp < 16; pp++) {
      const float4 v = *reinterpret_cast<const float4*>(&pb[b][pp * 64 + nl * 4]);
      p[pp][0] = v.x; p[pp][1] = v.y; p[pp][2] = v.z; p[pp][3] = v.w;
    }
    #pragma unroll
    for (int ot = 0; ot < 4; ot++) {
      const int o = o0 + ot;
      #pragma unroll
      for (int cv = 0; cv < 4; cv++) {
        const float4* wp = reinterpret_cast<const float4*>(&wb[b][o * 48 + cv * 12]);
        const float4 q0 = wp[0], q1 = wp[1], q2 = wp[2];
        const float wf[9] = {q0.x, q0.y, q0.z, q0.w, q1.x, q1.y, q1.z, q1.w, q2.x};
        const int dy = cv >> 1, dx = cv & 1;
        #pragma unroll
        for (int k = 0; k < 9; k++) {
          const float wv = wf[k];
          #pragma unroll
          for (int e = 0; e < 4; e++)
            acc[ot][cv][e] += wv * p[(dy + k / 3) * 4 + (dx + k % 3)][e];
        }
      }
    }
    if (c < 15) {
      #pragma unroll
      for (int r = 0; r < 2; r++)
        *reinterpret_cast<float4*>(&pb[b ^ 1][(tid + 128 * r) * 4]) = ppre[r];
      #pragma unroll
      for (int r = 0; r < 3; r++)
        *reinterpret_cast<float4*>(&wb[b ^ 1][(tid + 128 * r) * 4]) = wpre[r];
    }
    __syncthreads();
  }

  #pragma unroll
  for (int ot = 0; ot < 4; ot++) {
    const int o = o0 + ot;
    float bias[4];
    #pragma unroll
    for (int cv = 0; cv < 4; cv++)
      bias[cv] = b2[o * 121 + (2 * i + (cv >> 1)) * 11 + (2 * j + (cv & 1))];
    float rr[4];
    #pragma unroll
    for (int e = 0; e < 4; e++) {
      float best = -1e30f;
      #pragma unroll
      for (int cv = 0; cv < 4; cv++)
        best = fmaxf(best, acc[ot][cv][e] + bias[cv]);
      rr[e] = fmaxf(best, 0.f);
    }
    const int ko = (o * 5 + i) * 5 + j;
    float4 res; res.x = rr[0]; res.y = rr[1]; res.z = rr[2]; res.w = rr[3];
    *reinterpret_cast<float4*>(&h2[ko * NB + n0 + nl * 4]) = res;
  }
}

// ---------------------------------------------------------------------------
// fused FC1(relu)+FC2.  h2 (800,N) -> out (N,10).  grid 256 (n-tile 16), 1/CU.
// fc1: thread (jg=tid>>4 -> 8 j, nl=tid&15 -> 1 n); w staged in LDS 32k-chunks,
// double-buffered. fc2 via LDS round-trip of the 128x16 h3 tile.
__global__ __launch_bounds__(256) void k_fc(const float* __restrict__ h2,
                                            const float* __restrict__ f1w,
                                            const float* __restrict__ f1b,
                                            const float* __restrict__ f2w,
                                            const float* __restrict__ f2b,
                                            float* __restrict__ out) {
  __shared__ __align__(16) float wch[2][4096];  // [kk32][j128], 16KB each
  __shared__ float sh3[128 * 17];               // padded h3 tile
  __shared__ float swf2[128 * 12];              // fc2 weights, 12-padded
  __shared__ float sb1[128];
  const int tid = threadIdx.x;
  const int jg = tid >> 4;
  const int nl = tid & 15;
  const int n0 = blockIdx.x * 16;
  const int n = n0 + nl;

  for (int idx = tid; idx < 1536; idx += 256) {
    const int kk = idx / 12, f = idx % 12;
    swf2[idx] = (f < 10) ? f2w[kk * 10 + f] : 0.f;
  }
  if (tid < 128) sb1[tid] = f1b[tid];
  #pragma unroll
  for (int r = 0; r < 4; r++) {
    const int idx = tid + 256 * r;
    *reinterpret_cast<float4*>(&wch[0][idx * 4]) =
        *reinterpret_cast<const float4*>(&f1w[idx * 4]);
  }
  __syncthreads();

  float acc[8];
  #pragma unroll
  for (int jj = 0; jj < 8; jj++) acc[jj] = 0.f;

  for (int ch = 0; ch < 25; ch++) {
    const int b = ch & 1;
    float4 wpre[4];
    if (ch < 24) {
      #pragma unroll
      for (int r = 0; r < 4; r++)
        wpre[r] = *reinterpret_cast<const float4*>(
            &f1w[(ch + 1) * 4096 + (tid + 256 * r) * 4]);
    }
    float av[32];
    #pragma unroll
    for (int kk = 0; kk < 32; kk++) av[kk] = h2[(ch * 32 + kk) * NB + n];
    #pragma unroll
    for (int kk = 0; kk < 32; kk++) {
      const float4* wr = reinterpret_cast<const float4*>(&wch[b][kk * 128 + jg * 8]);
      const float4 v0 = wr[0], v1 = wr[1];
      acc[0] += av[kk] * v0.x; acc[1] += av[kk] * v0.y;
      acc[2] += av[kk] * v0.z; acc[3] += av[kk] * v0.w;
      acc[4] += av[kk] * v1.x; acc[5] += av[kk] * v1.y;
      acc[6] += av[kk] * v1.z; acc[7] += av[kk] * v1.w;
    }
    if (ch < 24) {
      #pragma unroll
      for (int r = 0; r < 4; r++)
        *reinterpret_cast<float4*>(&wch[b ^ 1][(tid + 256 * r) * 4]) = wpre[r];
    }
    __syncthreads();
  }

  #pragma unroll
  for (int jj = 0; jj < 8; jj++) {
    const int j = jg * 8 + jj;
    sh3[j * 17 + nl] = fmaxf(acc[jj] + sb1[j], 0.f);
  }
  __syncthreads();
  if (tid < 160) {
    const int oo = tid >> 4;
    const int nn = tid & 15;
    float s = f2b[oo];
    for (int j = 0; j < 128; j++)
      s += sh3[j * 17 + nn] * swf2[j * 12 + oo];
    out[(n0 + nn) * 10 + oo] = s;
  }
}

// ---------------------------------------------------------------------------
extern "C" void kernel_launch(void* const* d_in, const int* in_sizes, int n_in,
                              void* d_out, int out_size, void* d_ws,
                              size_t ws_size, hipStream_t stream) {
  const float* x   = (const float*)d_in[0];
  const float* w1  = (const float*)d_in[1];
  const float* b1  = (const float*)d_in[2];
  const float* w2  = (const float*)d_in[3];
  const float* b2  = (const float*)d_in[4];
  const float* f1w = (const float*)d_in[5];
  const float* f1b = (const float*)d_in[6];
  const float* f2w = (const float*)d_in[7];
  const float* f2b = (const float*)d_in[8];
  float* out = (float*)d_out;
  char* ws = (char*)d_ws;
  float* xT  = (float*)(ws + XT_OFF);
  float* h1  = (float*)(ws + H1_OFF);
  float* h2  = (float*)(ws + H2_OFF);
  float* w2r = (float*)(ws + W2R_OFF);

  k_prep<<<5600, 256, 0, stream>>>(x, w2, xT, w2r);
  k_lc1<<<dim3(16, 169), 256, 0, stream>>>(xT, w1, b1, h1);
  k_lc2<<<dim3(64, 25), 128, 0, stream>>>(h1, w2r, b2, h2);
  k_fc<<<256, 256, 0, stream>>>(h2, f1w, f1b, f2w, f2b, out);
}

// Round 4
// 253.992 us; speedup vs baseline: 1.0783x; 1.0783x over previous
//
#include <hip/hip_runtime.h>
#include <hip/hip_bf16.h>

#define NB 4096

// workspace layout (bytes, 16B-aligned)
#define XT_OFF  0u           // 784*4096*4      = 12,845,056
#define H1_OFF  12845056u    // 16*169*4096*4   = 44,302,336
#define H2_OFF  57147392u    // 800*4096*4      = 13,107,200
#define W2R_OFF 70254592u    // 25*16*4*32*12*4 =  2,457,600
// end 72,712,192

// ---------------------------------------------------------------------------
// fused prep: blocks [0,3200) transpose x -> xT; blocks [3200,5600) gather w2
// w2r layout: [pos25][c16][cv4][o32][12pad]  (cv-major: og LDS stride 48 dw
// == 16 mod 32 banks -> 2-way = conflict-free; o-major's 192 == 0 mod 32 was
// the R3 4-way-conflict bug)
__global__ __launch_bounds__(256) void k_prep(const float* __restrict__ x,
                                              const float* __restrict__ w2,
                                              float* __restrict__ xT,
                                              float* __restrict__ w2r) {
  const int bx = blockIdx.x;
  if (bx < 3200) {
    __shared__ float t[32][33];
    const int c0 = (bx % 25) * 32;
    const int n0 = (bx / 25) * 32;
    const int tx = threadIdx.x & 31, ty = threadIdx.x >> 5;
    #pragma unroll
    for (int i = 0; i < 32; i += 8) {
      const int c = c0 + tx;
      if (c < 784) t[ty + i][tx] = x[(n0 + ty + i) * 784 + c];
    }
    __syncthreads();
    #pragma unroll
    for (int i = 0; i < 32; i += 8) {
      const int c = c0 + ty + i;
      if (c < 784) xT[c * NB + n0 + tx] = t[tx][ty + i];
    }
  } else {
    const int idx = (bx - 3200) * 256 + threadIdx.x;  // 614,400 elems
    const int pos = idx / 24576;
    const int r1 = idx % 24576;
    const int c = r1 / 1536;
    const int r2 = r1 % 1536;
    const int cv = r2 / 384;
    const int r3 = r2 % 384;
    const int o = r3 / 12;
    const int k = r3 % 12;
    float v = 0.f;
    if (k < 9) {
      const int i = pos / 5, j = pos % 5;
      const int y = 2 * i + (cv >> 1), xx = 2 * j + (cv & 1);
      v = w2[((o * 16 + c) * 9 + k) * 121 + y * 11 + xx];
    }
    w2r[idx] = v;
  }
}

// ---------------------------------------------------------------------------
// LC1 + ReLU + pool.  xT (784,N) -> h1 (16,13,13,N)
// block 256 = 4 og (4 o, wave-uniform) x 64 nl (4 n); grid (16 nt, 169 pos)
__global__ __launch_bounds__(256, 3) void k_lc1(const float* __restrict__ xT,
                                                const float* __restrict__ w1,
                                                const float* __restrict__ b1,
                                                float* __restrict__ h1) {
  __shared__ __align__(16) float sw[640];  // [o16][36] + bias [o][conv] at 576
  const int pos = blockIdx.y;
  const int i = pos / 13, j = pos % 13;
  const int tid = threadIdx.x;
  const int og = tid >> 6, nl = tid & 63;
  const int o0 = og * 4;
  const int n = blockIdx.x * 256 + nl * 4;

  for (int idx = tid; idx < 640; idx += 256) {
    float v;
    if (idx < 576) {
      const int o = idx / 36, t = idx % 36;
      const int cv = t / 9, k = t % 9;
      const int y = 2 * i + (cv >> 1), xx = 2 * j + (cv & 1);
      v = w1[(o * 9 + k) * 676 + y * 26 + xx];
    } else {
      const int r = idx - 576;
      const int o = r >> 2, cv = r & 3;
      v = b1[(o * 26 + 2 * i + (cv >> 1)) * 26 + 2 * j + (cv & 1)];
    }
    sw[idx] = v;
  }
  __syncthreads();

  float p[16][4];
  #pragma unroll
  for (int r = 0; r < 4; r++)
    #pragma unroll
    for (int cc = 0; cc < 4; cc++) {
      const float4 v = *reinterpret_cast<const float4*>(
          &xT[((2 * i + r) * 28 + (2 * j + cc)) * NB + n]);
      p[r * 4 + cc][0] = v.x; p[r * 4 + cc][1] = v.y;
      p[r * 4 + cc][2] = v.z; p[r * 4 + cc][3] = v.w;
    }

  #pragma unroll
  for (int ot = 0; ot < 4; ot++) {
    const int o = o0 + ot;
    float wf[36];
    const float4* wp = reinterpret_cast<const float4*>(&sw[o * 36]);
    #pragma unroll
    for (int q = 0; q < 9; q++) {
      const float4 v = wp[q];
      wf[4 * q] = v.x; wf[4 * q + 1] = v.y;
      wf[4 * q + 2] = v.z; wf[4 * q + 3] = v.w;
    }
    float s[4][4];
    #pragma unroll
    for (int cv = 0; cv < 4; cv++)
      #pragma unroll
      for (int e = 0; e < 4; e++) s[cv][e] = 0.f;
    #pragma unroll
    for (int cv = 0; cv < 4; cv++) {
      const int dy = cv >> 1, dx = cv & 1;
      #pragma unroll
      for (int k = 0; k < 9; k++) {
        const float wv = wf[cv * 9 + k];
        #pragma unroll
        for (int e = 0; e < 4; e++)
          s[cv][e] += wv * p[(dy + k / 3) * 4 + (dx + k % 3)][e];
      }
    }
    float rr[4];
    #pragma unroll
    for (int e = 0; e < 4; e++) {
      float best = -1e30f;
      #pragma unroll
      for (int cv = 0; cv < 4; cv++)
        best = fmaxf(best, s[cv][e] + sw[576 + o * 4 + cv]);
      rr[e] = fmaxf(best, 0.f);
    }
    float4 res; res.x = rr[0]; res.y = rr[1]; res.z = rr[2]; res.w = rr[3];
    *reinterpret_cast<float4*>(&h1[((o * 13 + i) * 13 + j) * NB + n]) = res;
  }
}

// ---------------------------------------------------------------------------
// LC2 + ReLU + pool.  h1 (16,169,N) -> h2 (800,N)
// block 128 = 8 og (4 o) x 16 nl (4 n); grid (64 nt, 25 pos), nt fastest.
// Patches AND weights LDS-staged, double-buffered via register prefetch.
// __launch_bounds__(128,2): VGPR cap 256 -> no scratch spill (R3 bug: default
// budget allocated 84 VGPRs and spilled ~157MB/dispatch to scratch).
__global__ __launch_bounds__(128, 2) void k_lc2(const float* __restrict__ h1,
                                                const float* __restrict__ w2r,
                                                const float* __restrict__ b2,
                                                float* __restrict__ h2) {
  __shared__ __align__(16) float pb[2][16 * 64];  // patches [pp16][n64], 4KB ea
  __shared__ __align__(16) float wb[2][1536];     // weights [cv4][o32][12], 6KB ea
  const int pos = blockIdx.y;
  const int i = pos / 5, j = pos % 5;
  const int tid = threadIdx.x;
  const int og = tid >> 4;   // 0..7
  const int nl = tid & 15;
  const int o0 = og * 4;
  const int n0 = blockIdx.x * 64;
  const float* wsrc = w2r + pos * 24576;

  // stage c = 0
  #pragma unroll
  for (int r = 0; r < 2; r++) {
    const int idx = tid + 128 * r;
    const int pp = idx >> 4, q = idx & 15;
    *reinterpret_cast<float4*>(&pb[0][idx * 4]) =
        *reinterpret_cast<const float4*>(
            &h1[((2 * i + (pp >> 2)) * 13 + (2 * j + (pp & 3))) * NB + n0 + q * 4]);
  }
  #pragma unroll
  for (int r = 0; r < 3; r++) {
    const int idx = tid + 128 * r;
    *reinterpret_cast<float4*>(&wb[0][idx * 4]) =
        *reinterpret_cast<const float4*>(&wsrc[idx * 4]);
  }
  __syncthreads();

  float acc[4][4][4];  // [ot][cv][e]
  #pragma unroll
  for (int ot = 0; ot < 4; ot++)
    #pragma unroll
    for (int cv = 0; cv < 4; cv++)
      #pragma unroll
      for (int e = 0; e < 4; e++) acc[ot][cv][e] = 0.f;

  for (int c = 0; c < 16; c++) {
    const int b = c & 1;
    float4 ppre[2], wpre[3];
    if (c < 15) {
      #pragma unroll
      for (int r = 0; r < 2; r++) {
        const int idx = tid + 128 * r;
        const int pp = idx >> 4, q = idx & 15;
        ppre[r] = *reinterpret_cast<const float4*>(
            &h1[((c + 1) * 169 + (2 * i + (pp >> 2)) * 13 + (2 * j + (pp & 3))) * NB +
                n0 + q * 4]);
      }
      #pragma unroll
      for (int r = 0; r < 3; r++)
        wpre[r] = *reinterpret_cast<const float4*>(
            &wsrc[(c + 1) * 1536 + (tid + 128 * r) * 4]);
    }
    // patches from LDS (og broadcast free; nl 2-way aliasing free)
    float p[16][4];
    #pragma unroll
    for (int pp = 0; pp < 16; pp++) {
      const float4 v = *reinterpret_cast<const float4*>(&pb[b][pp * 64 + nl * 4]);
      p[pp][0] = v.x; p[pp][1] = v.y; p[pp][2] = v.z; p[pp][3] = v.w;
    }
    #pragma unroll
    for (int ot = 0; ot < 4; ot++) {
      const int o = o0 + ot;
      #pragma unroll
      for (int cv = 0; cv < 4; cv++) {
        const float4* wp = reinterpret_cast<const float4*>(&wb[b][(cv * 32 + o) * 12]);
        const float4 q0 = wp[0], q1 = wp[1], q2 = wp[2];
        const float wf[9] = {q0.x, q0.y, q0.z, q0.w, q1.x, q1.y, q1.z, q1.w, q2.x};
        const int dy = cv >> 1, dx = cv & 1;
        #pragma unroll
        for (int k = 0; k < 9; k++) {
          const float wv = wf[k];
          #pragma unroll
          for (int e = 0; e < 4; e++)
            acc[ot][cv][e] += wv * p[(dy + k / 3) * 4 + (dx + k % 3)][e];
        }
      }
    }
    if (c < 15) {
      #pragma unroll
      for (int r = 0; r < 2; r++)
        *reinterpret_cast<float4*>(&pb[b ^ 1][(tid + 128 * r) * 4]) = ppre[r];
      #pragma unroll
      for (int r = 0; r < 3; r++)
        *reinterpret_cast<float4*>(&wb[b ^ 1][(tid + 128 * r) * 4]) = wpre[r];
    }
    __syncthreads();
  }

  #pragma unroll
  for (int ot = 0; ot < 4; ot++) {
    const int o = o0 + ot;
    float bias[4];
    #pragma unroll
    for (int cv = 0; cv < 4; cv++)
      bias[cv] = b2[o * 121 + (2 * i + (cv >> 1)) * 11 + (2 * j + (cv & 1))];
    float rr[4];
    #pragma unroll
    for (int e = 0; e < 4; e++) {
      float best = -1e30f;
      #pragma unroll
      for (int cv = 0; cv < 4; cv++)
        best = fmaxf(best, acc[ot][cv][e] + bias[cv]);
      rr[e] = fmaxf(best, 0.f);
    }
    const int ko = (o * 5 + i) * 5 + j;
    float4 res; res.x = rr[0]; res.y = rr[1]; res.z = rr[2]; res.w = rr[3];
    *reinterpret_cast<float4*>(&h2[ko * NB + n0 + nl * 4]) = res;
  }
}

// ---------------------------------------------------------------------------
// fused FC1(relu)+FC2.  h2 (800,N) -> out (N,10).  grid 256 (n-tile 16), 1/CU.
__global__ __launch_bounds__(256) void k_fc(const float* __restrict__ h2,
                                            const float* __restrict__ f1w,
                                            const float* __restrict__ f1b,
                                            const float* __restrict__ f2w,
                                            const float* __restrict__ f2b,
                                            float* __restrict__ out) {
  __shared__ __align__(16) float wch[2][4096];  // [kk32][j128], 16KB each
  __shared__ float sh3[128 * 17];               // padded h3 tile
  __shared__ float swf2[128 * 12];              // fc2 weights, 12-padded
  __shared__ float sb1[128];
  const int tid = threadIdx.x;
  const int jg = tid >> 4;
  const int nl = tid & 15;
  const int n0 = blockIdx.x * 16;
  const int n = n0 + nl;

  for (int idx = tid; idx < 1536; idx += 256) {
    const int kk = idx / 12, f = idx % 12;
    swf2[idx] = (f < 10) ? f2w[kk * 10 + f] : 0.f;
  }
  if (tid < 128) sb1[tid] = f1b[tid];
  #pragma unroll
  for (int r = 0; r < 4; r++) {
    const int idx = tid + 256 * r;
    *reinterpret_cast<float4*>(&wch[0][idx * 4]) =
        *reinterpret_cast<const float4*>(&f1w[idx * 4]);
  }
  __syncthreads();

  float acc[8];
  #pragma unroll
  for (int jj = 0; jj < 8; jj++) acc[jj] = 0.f;

  for (int ch = 0; ch < 25; ch++) {
    const int b = ch & 1;
    float4 wpre[4];
    if (ch < 24) {
      #pragma unroll
      for (int r = 0; r < 4; r++)
        wpre[r] = *reinterpret_cast<const float4*>(
            &f1w[(ch + 1) * 4096 + (tid + 256 * r) * 4]);
    }
    float av[32];
    #pragma unroll
    for (int kk = 0; kk < 32; kk++) av[kk] = h2[(ch * 32 + kk) * NB + n];
    #pragma unroll
    for (int kk = 0; kk < 32; kk++) {
      const float4* wr = reinterpret_cast<const float4*>(&wch[b][kk * 128 + jg * 8]);
      const float4 v0 = wr[0], v1 = wr[1];
      acc[0] += av[kk] * v0.x; acc[1] += av[kk] * v0.y;
      acc[2] += av[kk] * v0.z; acc[3] += av[kk] * v0.w;
      acc[4] += av[kk] * v1.x; acc[5] += av[kk] * v1.y;
      acc[6] += av[kk] * v1.z; acc[7] += av[kk] * v1.w;
    }
    if (ch < 24) {
      #pragma unroll
      for (int r = 0; r < 4; r++)
        *reinterpret_cast<float4*>(&wch[b ^ 1][(tid + 256 * r) * 4]) = wpre[r];
    }
    __syncthreads();
  }

  #pragma unroll
  for (int jj = 0; jj < 8; jj++) {
    const int j = jg * 8 + jj;
    sh3[j * 17 + nl] = fmaxf(acc[jj] + sb1[j], 0.f);
  }
  __syncthreads();
  if (tid < 160) {
    const int oo = tid >> 4;
    const int nn = tid & 15;
    float s = f2b[oo];
    for (int j = 0; j < 128; j++)
      s += sh3[j * 17 + nn] * swf2[j * 12 + oo];
    out[(n0 + nn) * 10 + oo] = s;
  }
}

// ---------------------------------------------------------------------------
extern "C" void kernel_launch(void* const* d_in, const int* in_sizes, int n_in,
                              void* d_out, int out_size, void* d_ws,
                              size_t ws_size, hipStream_t stream) {
  const float* x   = (const float*)d_in[0];
  const float* w1  = (const float*)d_in[1];
  const float* b1  = (const float*)d_in[2];
  const float* w2  = (const float*)d_in[3];
  const float* b2  = (const float*)d_in[4];
  const float* f1w = (const float*)d_in[5];
  const float* f1b = (const float*)d_in[6];
  const float* f2w = (const float*)d_in[7];
  const float* f2b = (const float*)d_in[8];
  float* out = (float*)d_out;
  char* ws = (char*)d_ws;
  float* xT  = (float*)(ws + XT_OFF);
  float* h1  = (float*)(ws + H1_OFF);
  float* h2  = (float*)(ws + H2_OFF);
  float* w2r = (float*)(ws + W2R_OFF);

  k_prep<<<5600, 256, 0, stream>>>(x, w2, xT, w2r);
  k_lc1<<<dim3(16, 169), 256, 0, stream>>>(xT, w1, b1, h1);
  k_lc2<<<dim3(64, 25), 128, 0, stream>>>(h1, w2r, b2, h2);
  k_fc<<<256, 256, 0, stream>>>(h2, f1w, f1b, f2w, f2b, out);
}

// Round 5
// 233.583 us; speedup vs baseline: 1.1725x; 1.0874x over previous
//
#include <hip/hip_runtime.h>
#include <hip/hip_bf16.h>

#define NB 4096

// workspace layout (bytes, 16B-aligned)
#define XT_OFF  0u           // 784*4096*4      = 12,845,056
#define H1_OFF  12845056u    // 16*169*4096*4   = 44,302,336
#define H2_OFF  57147392u    // 800*4096*4      = 13,107,200
#define W2R_OFF 70254592u    // 25*16*4*32*12*4 =  2,457,600
// end 72,712,192

// ---------------------------------------------------------------------------
// fused prep: blocks [0,3200) transpose x -> xT; blocks [3200,5600) gather w2
// w2r layout: [pos25][c16][cv4][o32][12pad]
__global__ __launch_bounds__(256) void k_prep(const float* __restrict__ x,
                                              const float* __restrict__ w2,
                                              float* __restrict__ xT,
                                              float* __restrict__ w2r) {
  const int bx = blockIdx.x;
  if (bx < 3200) {
    __shared__ float t[32][33];
    const int c0 = (bx % 25) * 32;
    const int n0 = (bx / 25) * 32;
    const int tx = threadIdx.x & 31, ty = threadIdx.x >> 5;
    #pragma unroll
    for (int i = 0; i < 32; i += 8) {
      const int c = c0 + tx;
      if (c < 784) t[ty + i][tx] = x[(n0 + ty + i) * 784 + c];
    }
    __syncthreads();
    #pragma unroll
    for (int i = 0; i < 32; i += 8) {
      const int c = c0 + ty + i;
      if (c < 784) xT[c * NB + n0 + tx] = t[tx][ty + i];
    }
  } else {
    const int idx = (bx - 3200) * 256 + threadIdx.x;  // 614,400 elems
    const int pos = idx / 24576;
    const int r1 = idx % 24576;
    const int c = r1 / 1536;
    const int r2 = r1 % 1536;
    const int cv = r2 / 384;
    const int r3 = r2 % 384;
    const int o = r3 / 12;
    const int k = r3 % 12;
    float v = 0.f;
    if (k < 9) {
      const int i = pos / 5, j = pos % 5;
      const int y = 2 * i + (cv >> 1), xx = 2 * j + (cv & 1);
      v = w2[((o * 16 + c) * 9 + k) * 121 + y * 11 + xx];
    }
    w2r[idx] = v;
  }
}

// ---------------------------------------------------------------------------
// LC1 + ReLU + pool.  xT (784,N) -> h1 (16,13,13,N)
// block 256 = 4 og (4 o, wave-uniform) x 64 nl (4 n); grid (16 nt, 169 pos)
__global__ __launch_bounds__(256, 3) void k_lc1(const float* __restrict__ xT,
                                                const float* __restrict__ w1,
                                                const float* __restrict__ b1,
                                                float* __restrict__ h1) {
  __shared__ __align__(16) float sw[640];  // [o16][36] + bias [o][conv] at 576
  const int pos = blockIdx.y;
  const int i = pos / 13, j = pos % 13;
  const int tid = threadIdx.x;
  const int og = tid >> 6, nl = tid & 63;
  const int o0 = og * 4;
  const int n = blockIdx.x * 256 + nl * 4;

  for (int idx = tid; idx < 640; idx += 256) {
    float v;
    if (idx < 576) {
      const int o = idx / 36, t = idx % 36;
      const int cv = t / 9, k = t % 9;
      const int y = 2 * i + (cv >> 1), xx = 2 * j + (cv & 1);
      v = w1[(o * 9 + k) * 676 + y * 26 + xx];
    } else {
      const int r = idx - 576;
      const int o = r >> 2, cv = r & 3;
      v = b1[(o * 26 + 2 * i + (cv >> 1)) * 26 + 2 * j + (cv & 1)];
    }
    sw[idx] = v;
  }
  __syncthreads();

  float p[16][4];
  #pragma unroll
  for (int r = 0; r < 4; r++)
    #pragma unroll
    for (int cc = 0; cc < 4; cc++) {
      const float4 v = *reinterpret_cast<const float4*>(
          &xT[((2 * i + r) * 28 + (2 * j + cc)) * NB + n]);
      p[r * 4 + cc][0] = v.x; p[r * 4 + cc][1] = v.y;
      p[r * 4 + cc][2] = v.z; p[r * 4 + cc][3] = v.w;
    }

  #pragma unroll
  for (int ot = 0; ot < 4; ot++) {
    const int o = o0 + ot;
    float wf[36];
    const float4* wp = reinterpret_cast<const float4*>(&sw[o * 36]);
    #pragma unroll
    for (int q = 0; q < 9; q++) {
      const float4 v = wp[q];
      wf[4 * q] = v.x; wf[4 * q + 1] = v.y;
      wf[4 * q + 2] = v.z; wf[4 * q + 3] = v.w;
    }
    float s[4][4];
    #pragma unroll
    for (int cv = 0; cv < 4; cv++)
      #pragma unroll
      for (int e = 0; e < 4; e++) s[cv][e] = 0.f;
    #pragma unroll
    for (int cv = 0; cv < 4; cv++) {
      const int dy = cv >> 1, dx = cv & 1;
      #pragma unroll
      for (int k = 0; k < 9; k++) {
        const float wv = wf[cv * 9 + k];
        #pragma unroll
        for (int e = 0; e < 4; e++)
          s[cv][e] += wv * p[(dy + k / 3) * 4 + (dx + k % 3)][e];
      }
    }
    float rr[4];
    #pragma unroll
    for (int e = 0; e < 4; e++) {
      float best = -1e30f;
      #pragma unroll
      for (int cv = 0; cv < 4; cv++)
        best = fmaxf(best, s[cv][e] + sw[576 + o * 4 + cv]);
      rr[e] = fmaxf(best, 0.f);
    }
    float4 res; res.x = rr[0]; res.y = rr[1]; res.z = rr[2]; res.w = rr[3];
    *reinterpret_cast<float4*>(&h1[((o * 13 + i) * 13 + j) * NB + n]) = res;
  }
}

// ---------------------------------------------------------------------------
// LC2 + ReLU + pool.  h1 (16,169,N) -> h2 (800,N)
// block 256 = 4 waves; WAVE = o-group (4 o), lane = n-position (4 n each,
// n-tile 256). Weights are wave-uniform -> direct VMEM broadcast loads from
// L2 (off the LDS pipe entirely). Patches LDS double-buffered; one b128 read
// serves the whole 64-lane wave. grid (16 nt, 25 pos, 2 oh).
__global__ __launch_bounds__(256, 2) void k_lc2(const float* __restrict__ h1,
                                                const float* __restrict__ w2r,
                                                const float* __restrict__ b2,
                                                float* __restrict__ h2) {
  __shared__ __align__(16) float pb[2][16 * 256];  // [pp16][n256], 16KB each
  const int pos = blockIdx.y;
  const int i = pos / 5, j = pos % 5;
  const int tid = threadIdx.x;
  const int lane = tid & 63;
  const int og = __builtin_amdgcn_readfirstlane(tid >> 6);  // wave id 0..3
  const int oh = blockIdx.z;
  const int o0 = oh * 16 + og * 4;
  const int n0 = blockIdx.x * 256;
  const int nl4 = lane * 4;
  const float* wpos = w2r + pos * 24576;

  // stage c = 0 patches: wave og loads patch-column px=og, rows 0..3
  #pragma unroll
  for (int r = 0; r < 4; r++) {
    *reinterpret_cast<float4*>(&pb[0][(r * 4 + og) * 256 + nl4]) =
        *reinterpret_cast<const float4*>(
            &h1[((2 * i + r) * 13 + (2 * j + og)) * NB + n0 + nl4]);
  }
  __syncthreads();

  float acc[4][4][4];  // [ot][cv][e]
  #pragma unroll
  for (int ot = 0; ot < 4; ot++)
    #pragma unroll
    for (int cv = 0; cv < 4; cv++)
      #pragma unroll
      for (int e = 0; e < 4; e++) acc[ot][cv][e] = 0.f;

  for (int c = 0; c < 16; c++) {
    const int b = c & 1;
    // branch-free register prefetch of next c's patch column
    const int cn = (c < 15) ? c + 1 : 15;
    float4 ppre[4];
    #pragma unroll
    for (int r = 0; r < 4; r++)
      ppre[r] = *reinterpret_cast<const float4*>(
          &h1[(cn * 169 + (2 * i + r) * 13 + (2 * j + og)) * NB + n0 + nl4]);

    // patches from LDS: 16 conflict-free b128, all lanes distinct banks
    float p[16][4];
    #pragma unroll
    for (int pp = 0; pp < 16; pp++) {
      const float4 v = *reinterpret_cast<const float4*>(&pb[b][pp * 256 + nl4]);
      p[pp][0] = v.x; p[pp][1] = v.y; p[pp][2] = v.z; p[pp][3] = v.w;
    }

    // weights: 12 wave-uniform float4 VMEM loads per cv (L1/L2 broadcast)
    #pragma unroll
    for (int cv = 0; cv < 4; cv++) {
      const float4* wq = reinterpret_cast<const float4*>(
          wpos + (c * 4 + cv) * 384 + o0 * 12);
      const int dy = cv >> 1, dx = cv & 1;
      #pragma unroll
      for (int ot = 0; ot < 4; ot++) {
        const float4 q0 = wq[ot * 3], q1 = wq[ot * 3 + 1], q2 = wq[ot * 3 + 2];
        const float wf[9] = {q0.x, q0.y, q0.z, q0.w,
                             q1.x, q1.y, q1.z, q1.w, q2.x};
        #pragma unroll
        for (int k = 0; k < 9; k++) {
          const float wv = wf[k];
          #pragma unroll
          for (int e = 0; e < 4; e++)
            acc[ot][cv][e] += wv * p[(dy + k / 3) * 4 + (dx + k % 3)][e];
        }
      }
    }

    // commit staged patches for c+1
    #pragma unroll
    for (int r = 0; r < 4; r++)
      *reinterpret_cast<float4*>(&pb[b ^ 1][(r * 4 + og) * 256 + nl4]) = ppre[r];
    __syncthreads();
  }

  #pragma unroll
  for (int ot = 0; ot < 4; ot++) {
    const int o = o0 + ot;
    float bias[4];
    #pragma unroll
    for (int cv = 0; cv < 4; cv++)
      bias[cv] = b2[o * 121 + (2 * i + (cv >> 1)) * 11 + (2 * j + (cv & 1))];
    float rr[4];
    #pragma unroll
    for (int e = 0; e < 4; e++) {
      float best = -1e30f;
      #pragma unroll
      for (int cv = 0; cv < 4; cv++)
        best = fmaxf(best, acc[ot][cv][e] + bias[cv]);
      rr[e] = fmaxf(best, 0.f);
    }
    const int ko = (o * 5 + i) * 5 + j;
    float4 res; res.x = rr[0]; res.y = rr[1]; res.z = rr[2]; res.w = rr[3];
    *reinterpret_cast<float4*>(&h2[ko * NB + n0 + nl4]) = res;
  }
}

// ---------------------------------------------------------------------------
// fused FC1(relu)+FC2.  h2 (800,N) -> out (N,10).  grid 256 (n-tile 16), 1/CU.
__global__ __launch_bounds__(256) void k_fc(const float* __restrict__ h2,
                                            const float* __restrict__ f1w,
                                            const float* __restrict__ f1b,
                                            const float* __restrict__ f2w,
                                            const float* __restrict__ f2b,
                                            float* __restrict__ out) {
  __shared__ __align__(16) float wch[2][4096];  // [kk32][j128], 16KB each
  __shared__ float sh3[128 * 17];               // padded h3 tile
  __shared__ float swf2[128 * 12];              // fc2 weights, 12-padded
  __shared__ float sb1[128];
  const int tid = threadIdx.x;
  const int jg = tid >> 4;
  const int nl = tid & 15;
  const int n0 = blockIdx.x * 16;
  const int n = n0 + nl;

  for (int idx = tid; idx < 1536; idx += 256) {
    const int kk = idx / 12, f = idx % 12;
    swf2[idx] = (f < 10) ? f2w[kk * 10 + f] : 0.f;
  }
  if (tid < 128) sb1[tid] = f1b[tid];
  #pragma unroll
  for (int r = 0; r < 4; r++) {
    const int idx = tid + 256 * r;
    *reinterpret_cast<float4*>(&wch[0][idx * 4]) =
        *reinterpret_cast<const float4*>(&f1w[idx * 4]);
  }
  __syncthreads();

  float acc[8];
  #pragma unroll
  for (int jj = 0; jj < 8; jj++) acc[jj] = 0.f;

  for (int ch = 0; ch < 25; ch++) {
    const int b = ch & 1;
    const int chn = (ch < 24) ? ch + 1 : 24;
    float4 wpre[4];
    #pragma unroll
    for (int r = 0; r < 4; r++)
      wpre[r] = *reinterpret_cast<const float4*>(
          &f1w[chn * 4096 + (tid + 256 * r) * 4]);
    float av[32];
    #pragma unroll
    for (int kk = 0; kk < 32; kk++) av[kk] = h2[(ch * 32 + kk) * NB + n];
    #pragma unroll
    for (int kk = 0; kk < 32; kk++) {
      const float4* wr = reinterpret_cast<const float4*>(&wch[b][kk * 128 + jg * 8]);
      const float4 v0 = wr[0], v1 = wr[1];
      acc[0] += av[kk] * v0.x; acc[1] += av[kk] * v0.y;
      acc[2] += av[kk] * v0.z; acc[3] += av[kk] * v0.w;
      acc[4] += av[kk] * v1.x; acc[5] += av[kk] * v1.y;
      acc[6] += av[kk] * v1.z; acc[7] += av[kk] * v1.w;
    }
    #pragma unroll
    for (int r = 0; r < 4; r++)
      *reinterpret_cast<float4*>(&wch[b ^ 1][(tid + 256 * r) * 4]) = wpre[r];
    __syncthreads();
  }

  #pragma unroll
  for (int jj = 0; jj < 8; jj++) {
    const int j = jg * 8 + jj;
    sh3[j * 17 + nl] = fmaxf(acc[jj] + sb1[j], 0.f);
  }
  __syncthreads();
  if (tid < 160) {
    const int oo = tid >> 4;
    const int nn = tid & 15;
    float s = f2b[oo];
    for (int j = 0; j < 128; j++)
      s += sh3[j * 17 + nn] * swf2[j * 12 + oo];
    out[(n0 + nn) * 10 + oo] = s;
  }
}

// ---------------------------------------------------------------------------
extern "C" void kernel_launch(void* const* d_in, const int* in_sizes, int n_in,
                              void* d_out, int out_size, void* d_ws,
                              size_t ws_size, hipStream_t stream) {
  const float* x   = (const float*)d_in[0];
  const float* w1  = (const float*)d_in[1];
  const float* b1  = (const float*)d_in[2];
  const float* w2  = (const float*)d_in[3];
  const float* b2  = (const float*)d_in[4];
  const float* f1w = (const float*)d_in[5];
  const float* f1b = (const float*)d_in[6];
  const float* f2w = (const float*)d_in[7];
  const float* f2b = (const float*)d_in[8];
  float* out = (float*)d_out;
  char* ws = (char*)d_ws;
  float* xT  = (float*)(ws + XT_OFF);
  float* h1  = (float*)(ws + H1_OFF);
  float* h2  = (float*)(ws + H2_OFF);
  float* w2r = (float*)(ws + W2R_OFF);

  k_prep<<<5600, 256, 0, stream>>>(x, w2, xT, w2r);
  k_lc1<<<dim3(16, 169), 256, 0, stream>>>(xT, w1, b1, h1);
  k_lc2<<<dim3(16, 25, 2), 256, 0, stream>>>(h1, w2r, b2, h2);
  k_fc<<<256, 256, 0, stream>>>(h2, f1w, f1b, f2w, f2b, out);
}

// Round 6
// 230.388 us; speedup vs baseline: 1.1888x; 1.0139x over previous
//
#include <hip/hip_runtime.h>
#include <hip/hip_bf16.h>

#define NB 4096

// workspace layout (bytes, 16B-aligned)
#define XT_OFF  0u           // 784*4096*4      = 12,845,056
#define H1_OFF  12845056u    // 16*169*4096*4   = 44,302,336
#define H2_OFF  57147392u    // 800*4096*4      = 13,107,200
#define W2R_OFF 70254592u    // 25*16*4*32*12*4 =  2,457,600
// end 72,712,192

// ---------------------------------------------------------------------------
// fused prep: blocks [0,3200) transpose x -> xT; blocks [3200,5600) gather w2
// w2r layout: [pos25][c16][cv4][o32][12pad]
__global__ __launch_bounds__(256) void k_prep(const float* __restrict__ x,
                                              const float* __restrict__ w2,
                                              float* __restrict__ xT,
                                              float* __restrict__ w2r) {
  const int bx = blockIdx.x;
  if (bx < 3200) {
    __shared__ float t[32][33];
    const int c0 = (bx % 25) * 32;
    const int n0 = (bx / 25) * 32;
    const int tx = threadIdx.x & 31, ty = threadIdx.x >> 5;
    #pragma unroll
    for (int i = 0; i < 32; i += 8) {
      const int c = c0 + tx;
      if (c < 784) t[ty + i][tx] = x[(n0 + ty + i) * 784 + c];
    }
    __syncthreads();
    #pragma unroll
    for (int i = 0; i < 32; i += 8) {
      const int c = c0 + ty + i;
      if (c < 784) xT[c * NB + n0 + tx] = t[tx][ty + i];
    }
  } else {
    const int idx = (bx - 3200) * 256 + threadIdx.x;  // 614,400 elems
    const int pos = idx / 24576;
    const int r1 = idx % 24576;
    const int c = r1 / 1536;
    const int r2 = r1 % 1536;
    const int cv = r2 / 384;
    const int r3 = r2 % 384;
    const int o = r3 / 12;
    const int k = r3 % 12;
    float v = 0.f;
    if (k < 9) {
      const int i = pos / 5, j = pos % 5;
      const int y = 2 * i + (cv >> 1), xx = 2 * j + (cv & 1);
      v = w2[((o * 16 + c) * 9 + k) * 121 + y * 11 + xx];
    }
    w2r[idx] = v;
  }
}

// ---------------------------------------------------------------------------
// LC1 + ReLU + pool.  xT (784,N) -> h1 (16,13,13,N)
// block 256 = 4 og (4 o, wave-uniform) x 64 nl (4 n); grid (16 nt, 169 pos)
__global__ __launch_bounds__(256, 3) void k_lc1(const float* __restrict__ xT,
                                                const float* __restrict__ w1,
                                                const float* __restrict__ b1,
                                                float* __restrict__ h1) {
  __shared__ __align__(16) float sw[640];  // [o16][36] + bias [o][conv] at 576
  const int pos = blockIdx.y;
  const int i = pos / 13, j = pos % 13;
  const int tid = threadIdx.x;
  const int og = tid >> 6, nl = tid & 63;
  const int o0 = og * 4;
  const int n = blockIdx.x * 256 + nl * 4;

  for (int idx = tid; idx < 640; idx += 256) {
    float v;
    if (idx < 576) {
      const int o = idx / 36, t = idx % 36;
      const int cv = t / 9, k = t % 9;
      const int y = 2 * i + (cv >> 1), xx = 2 * j + (cv & 1);
      v = w1[(o * 9 + k) * 676 + y * 26 + xx];
    } else {
      const int r = idx - 576;
      const int o = r >> 2, cv = r & 3;
      v = b1[(o * 26 + 2 * i + (cv >> 1)) * 26 + 2 * j + (cv & 1)];
    }
    sw[idx] = v;
  }
  __syncthreads();

  float p[16][4];
  #pragma unroll
  for (int r = 0; r < 4; r++)
    #pragma unroll
    for (int cc = 0; cc < 4; cc++) {
      const float4 v = *reinterpret_cast<const float4*>(
          &xT[((2 * i + r) * 28 + (2 * j + cc)) * NB + n]);
      p[r * 4 + cc][0] = v.x; p[r * 4 + cc][1] = v.y;
      p[r * 4 + cc][2] = v.z; p[r * 4 + cc][3] = v.w;
    }

  #pragma unroll
  for (int ot = 0; ot < 4; ot++) {
    const int o = o0 + ot;
    float wf[36];
    const float4* wp = reinterpret_cast<const float4*>(&sw[o * 36]);
    #pragma unroll
    for (int q = 0; q < 9; q++) {
      const float4 v = wp[q];
      wf[4 * q] = v.x; wf[4 * q + 1] = v.y;
      wf[4 * q + 2] = v.z; wf[4 * q + 3] = v.w;
    }
    float s[4][4];
    #pragma unroll
    for (int cv = 0; cv < 4; cv++)
      #pragma unroll
      for (int e = 0; e < 4; e++) s[cv][e] = 0.f;
    #pragma unroll
    for (int cv = 0; cv < 4; cv++) {
      const int dy = cv >> 1, dx = cv & 1;
      #pragma unroll
      for (int k = 0; k < 9; k++) {
        const float wv = wf[cv * 9 + k];
        #pragma unroll
        for (int e = 0; e < 4; e++)
          s[cv][e] += wv * p[(dy + k / 3) * 4 + (dx + k % 3)][e];
      }
    }
    float rr[4];
    #pragma unroll
    for (int e = 0; e < 4; e++) {
      float best = -1e30f;
      #pragma unroll
      for (int cv = 0; cv < 4; cv++)
        best = fmaxf(best, s[cv][e] + sw[576 + o * 4 + cv]);
      rr[e] = fmaxf(best, 0.f);
    }
    float4 res; res.x = rr[0]; res.y = rr[1]; res.z = rr[2]; res.w = rr[3];
    *reinterpret_cast<float4*>(&h1[((o * 13 + i) * 13 + j) * NB + n]) = res;
  }
}

// ---------------------------------------------------------------------------
// LC2 + ReLU + pool.  h1 (16,169,N) -> h2 (800,N)
// block 256 = 4 waves; wave = o-group (4 o), lane = n (4 each, n-tile 256).
// Weights wave-uniform (scalar loads) with EXPLICIT cv-granular software
// pipeline: wnext prefetched before the 144-FMA body consuming wcur -> the
// ~200cy scalar-load latency hides under 288cy of FMAs (R5 stall: per-cv
// s_load batch -> lgkmcnt -> FMA serialization, VALUBusy 31%).
// Patches LDS double-buffered. grid (16 nt, 25 pos, 2 oh).
__global__ __launch_bounds__(256, 2) void k_lc2(const float* __restrict__ h1,
                                                const float* __restrict__ w2r,
                                                const float* __restrict__ b2,
                                                float* __restrict__ h2) {
  __shared__ __align__(16) float pb[2][16 * 256];  // [pp16][n256], 16KB each
  const int pos = blockIdx.y;
  const int i = pos / 5, j = pos % 5;
  const int tid = threadIdx.x;
  const int lane = tid & 63;
  const int og = __builtin_amdgcn_readfirstlane(tid >> 6);  // wave id 0..3
  const int oh = blockIdx.z;
  const int o0 = oh * 16 + og * 4;
  const int n0 = blockIdx.x * 256;
  const int nl4 = lane * 4;
  const float* wbase = w2r + pos * 24576 + o0 * 12;  // (c,cv) chunk: +(c*4+cv)*384

  // stage c = 0 patches: wave og loads patch-column px=og, rows 0..3
  #pragma unroll
  for (int r = 0; r < 4; r++) {
    *reinterpret_cast<float4*>(&pb[0][(r * 4 + og) * 256 + nl4]) =
        *reinterpret_cast<const float4*>(
            &h1[((2 * i + r) * 13 + (2 * j + og)) * NB + n0 + nl4]);
  }

  // preload weights for (c=0, cv=0): 12 float4 = [ot4][q3]
  float4 wcur[12];
  #pragma unroll
  for (int t = 0; t < 12; t++)
    wcur[t] = *reinterpret_cast<const float4*>(
        wbase + (t / 3) * 12 + (t % 3) * 4);
  __syncthreads();

  float acc[4][4][4];  // [ot][cv][e]
  #pragma unroll
  for (int ot = 0; ot < 4; ot++)
    #pragma unroll
    for (int cv = 0; cv < 4; cv++)
      #pragma unroll
      for (int e = 0; e < 4; e++) acc[ot][cv][e] = 0.f;

  for (int c = 0; c < 16; c++) {
    const int b = c & 1;
    // branch-free register prefetch of next c's patch column
    const int cn = (c < 15) ? c + 1 : 15;
    float4 ppre[4];
    #pragma unroll
    for (int r = 0; r < 4; r++)
      ppre[r] = *reinterpret_cast<const float4*>(
          &h1[(cn * 169 + (2 * i + r) * 13 + (2 * j + og)) * NB + n0 + nl4]);

    // patches from LDS: 16 conflict-free b128
    float p[16][4];
    #pragma unroll
    for (int pp = 0; pp < 16; pp++) {
      const float4 v = *reinterpret_cast<const float4*>(&pb[b][pp * 256 + nl4]);
      p[pp][0] = v.x; p[pp][1] = v.y; p[pp][2] = v.z; p[pp][3] = v.w;
    }

    #pragma unroll
    for (int cv = 0; cv < 4; cv++) {
      // prefetch next (c,cv) weight chunk while consuming wcur
      const int lin = c * 4 + cv + 1;
      const int nidx = (lin < 64) ? lin : 63;
      float4 wnext[12];
      #pragma unroll
      for (int t = 0; t < 12; t++)
        wnext[t] = *reinterpret_cast<const float4*>(
            wbase + nidx * 384 + (t / 3) * 12 + (t % 3) * 4);

      const int dy = cv >> 1, dx = cv & 1;
      #pragma unroll
      for (int ot = 0; ot < 4; ot++) {
        const float4 q0 = wcur[ot * 3], q1 = wcur[ot * 3 + 1],
                     q2 = wcur[ot * 3 + 2];
        const float wf[9] = {q0.x, q0.y, q0.z, q0.w,
                             q1.x, q1.y, q1.z, q1.w, q2.x};
        #pragma unroll
        for (int k = 0; k < 9; k++) {
          const float wv = wf[k];
          #pragma unroll
          for (int e = 0; e < 4; e++)
            acc[ot][cv][e] += wv * p[(dy + k / 3) * 4 + (dx + k % 3)][e];
        }
      }
      #pragma unroll
      for (int t = 0; t < 12; t++) wcur[t] = wnext[t];
    }

    // commit staged patches for c+1
    #pragma unroll
    for (int r = 0; r < 4; r++)
      *reinterpret_cast<float4*>(&pb[b ^ 1][(r * 4 + og) * 256 + nl4]) = ppre[r];
    __syncthreads();
  }

  #pragma unroll
  for (int ot = 0; ot < 4; ot++) {
    const int o = o0 + ot;
    float bias[4];
    #pragma unroll
    for (int cv = 0; cv < 4; cv++)
      bias[cv] = b2[o * 121 + (2 * i + (cv >> 1)) * 11 + (2 * j + (cv & 1))];
    float rr[4];
    #pragma unroll
    for (int e = 0; e < 4; e++) {
      float best = -1e30f;
      #pragma unroll
      for (int cv = 0; cv < 4; cv++)
        best = fmaxf(best, acc[ot][cv][e] + bias[cv]);
      rr[e] = fmaxf(best, 0.f);
    }
    const int ko = (o * 5 + i) * 5 + j;
    float4 res; res.x = rr[0]; res.y = rr[1]; res.z = rr[2]; res.w = rr[3];
    *reinterpret_cast<float4*>(&h2[ko * NB + n0 + nl4]) = res;
  }
}

// ---------------------------------------------------------------------------
// fused FC1(relu)+FC2.  h2 (800,N) -> out (N,10).  grid 512 (n-tile 8) ->
// 2 blocks/CU for latency overlap (was 1).  thread = (jg=tid>>3 -> 4 j,
// nl=tid&7 -> 1 n).
__global__ __launch_bounds__(256) void k_fc(const float* __restrict__ h2,
                                            const float* __restrict__ f1w,
                                            const float* __restrict__ f1b,
                                            const float* __restrict__ f2w,
                                            const float* __restrict__ f2b,
                                            float* __restrict__ out) {
  __shared__ __align__(16) float wch[2][4096];  // [kk32][j128], 16KB each
  __shared__ float sh3[128 * 9];                // padded h3 tile [j128][n8+1]
  __shared__ float swf2[128 * 12];              // fc2 weights, 12-padded
  __shared__ float sb1[128];
  const int tid = threadIdx.x;
  const int jg = tid >> 3;   // 0..31, covers 4 j each
  const int nl = tid & 7;
  const int n0 = blockIdx.x * 8;
  const int n = n0 + nl;

  for (int idx = tid; idx < 1536; idx += 256) {
    const int kk = idx / 12, f = idx % 12;
    swf2[idx] = (f < 10) ? f2w[kk * 10 + f] : 0.f;
  }
  if (tid < 128) sb1[tid] = f1b[tid];
  #pragma unroll
  for (int r = 0; r < 4; r++) {
    const int idx = tid + 256 * r;
    *reinterpret_cast<float4*>(&wch[0][idx * 4]) =
        *reinterpret_cast<const float4*>(&f1w[idx * 4]);
  }
  __syncthreads();

  float acc[4];
  #pragma unroll
  for (int jj = 0; jj < 4; jj++) acc[jj] = 0.f;

  for (int ch = 0; ch < 25; ch++) {
    const int b = ch & 1;
    const int chn = (ch < 24) ? ch + 1 : 24;
    float4 wpre[4];
    #pragma unroll
    for (int r = 0; r < 4; r++)
      wpre[r] = *reinterpret_cast<const float4*>(
          &f1w[chn * 4096 + (tid + 256 * r) * 4]);
    float av[32];
    #pragma unroll
    for (int kk = 0; kk < 32; kk++) av[kk] = h2[(ch * 32 + kk) * NB + n];
    #pragma unroll
    for (int kk = 0; kk < 32; kk++) {
      const float4 v =
          *reinterpret_cast<const float4*>(&wch[b][kk * 128 + jg * 4]);
      acc[0] += av[kk] * v.x; acc[1] += av[kk] * v.y;
      acc[2] += av[kk] * v.z; acc[3] += av[kk] * v.w;
    }
    #pragma unroll
    for (int r = 0; r < 4; r++)
      *reinterpret_cast<float4*>(&wch[b ^ 1][(tid + 256 * r) * 4]) = wpre[r];
    __syncthreads();
  }

  #pragma unroll
  for (int jj = 0; jj < 4; jj++) {
    const int j = jg * 4 + jj;
    sh3[j * 9 + nl] = fmaxf(acc[jj] + sb1[j], 0.f);
  }
  __syncthreads();
  if (tid < 80) {
    const int oo = tid >> 3;
    const int nn = tid & 7;
    float s = f2b[oo];
    for (int j = 0; j < 128; j++)
      s += sh3[j * 9 + nn] * swf2[j * 12 + oo];
    out[(n0 + nn) * 10 + oo] = s;
  }
}

// ---------------------------------------------------------------------------
extern "C" void kernel_launch(void* const* d_in, const int* in_sizes, int n_in,
                              void* d_out, int out_size, void* d_ws,
                              size_t ws_size, hipStream_t stream) {
  const float* x   = (const float*)d_in[0];
  const float* w1  = (const float*)d_in[1];
  const float* b1  = (const float*)d_in[2];
  const float* w2  = (const float*)d_in[3];
  const float* b2  = (const float*)d_in[4];
  const float* f1w = (const float*)d_in[5];
  const float* f1b = (const float*)d_in[6];
  const float* f2w = (const float*)d_in[7];
  const float* f2b = (const float*)d_in[8];
  float* out = (float*)d_out;
  char* ws = (char*)d_ws;
  float* xT  = (float*)(ws + XT_OFF);
  float* h1  = (float*)(ws + H1_OFF);
  float* h2  = (float*)(ws + H2_OFF);
  float* w2r = (float*)(ws + W2R_OFF);

  k_prep<<<5600, 256, 0, stream>>>(x, w2, xT, w2r);
  k_lc1<<<dim3(16, 169), 256, 0, stream>>>(xT, w1, b1, h1);
  k_lc2<<<dim3(16, 25, 2), 256, 0, stream>>>(h1, w2r, b2, h2);
  k_fc<<<512, 256, 0, stream>>>(h2, f1w, f1b, f2w, f2b, out);
}

// Round 7
// 193.146 us; speedup vs baseline: 1.4180x; 1.1928x over previous
//
#include <hip/hip_runtime.h>

#define NB 4096

typedef __attribute__((ext_vector_type(8))) short s8v;   // 8 bf16 (4 VGPR)
typedef __attribute__((ext_vector_type(4))) short s4v;   // 4 bf16
typedef __attribute__((ext_vector_type(4))) float f4v;   // MFMA acc

// workspace layout (bytes, 16B-aligned)
#define XT_OFF  0u           // 784*4096*4          = 12,845,056
#define H1B_OFF 12845056u    // 169*4096*16*2 bf16  = 22,151,168
#define H2_OFF  35000320u    // 800*4096*4          = 13,107,200
#define W2B_OFF 48107520u    // 25*4*8*2*64*8*2     =  1,638,400
#define B2R_OFF 49745920u    // 25*32*4*4           =     12,800

__device__ __forceinline__ unsigned short f2bf(float f) {
  unsigned int u = __builtin_bit_cast(unsigned int, f);
  u += 0x7fffu + ((u >> 16) & 1u);
  return (unsigned short)(u >> 16);
}

// ---------------------------------------------------------------------------
// prep: [0,3200) transpose x->xT; [3200,6400) w2 -> w2b (bf16, MFMA B-frag
// order [pos][cv][s][ot][lane][8], K=256 ordered (py,px,c), zero outside the
// cv 3x3 window); block 6400: b2 -> b2r [pos][o][cv] fp32.
__global__ __launch_bounds__(256) void k_prep(const float* __restrict__ x,
                                              const float* __restrict__ w2,
                                              const float* __restrict__ b2,
                                              float* __restrict__ xT,
                                              short* __restrict__ w2b,
                                              float* __restrict__ b2r) {
  const int bx = blockIdx.x;
  if (bx < 3200) {
    __shared__ float t[32][33];
    const int c0 = (bx % 25) * 32;
    const int n0 = (bx / 25) * 32;
    const int tx = threadIdx.x & 31, ty = threadIdx.x >> 5;
    #pragma unroll
    for (int i = 0; i < 32; i += 8) {
      const int c = c0 + tx;
      if (c < 784) t[ty + i][tx] = x[(n0 + ty + i) * 784 + c];
    }
    __syncthreads();
    #pragma unroll
    for (int i = 0; i < 32; i += 8) {
      const int c = c0 + ty + i;
      if (c < 784) xT[c * NB + n0 + tx] = t[tx][ty + i];
    }
  } else if (bx < 6400) {
    const int idx = (bx - 3200) * 256 + threadIdx.x;  // 819,200 elems
    const int t = idx & 7;
    const int l = (idx >> 3) & 63;
    const int ot = (idx >> 9) & 1;
    const int s = (idx >> 10) & 7;
    const int cv = (idx >> 13) & 3;
    const int pos = idx >> 15;
    const int k = s * 32 + (l >> 4) * 8 + t;
    const int o = ot * 16 + (l & 15);
    const int w = k >> 4, c = k & 15;
    const int py = w >> 2, px = w & 3;
    const int dy = cv >> 1, dx = cv & 1;
    const int ky = py - dy, kx = px - dx;
    const int I = pos / 5, J = pos % 5;
    float v = 0.f;
    if (ky >= 0 && ky < 3 && kx >= 0 && kx < 3)
      v = w2[((o * 16 + c) * 9 + ky * 3 + kx) * 121 +
             (2 * I + dy) * 11 + (2 * J + dx)];
    w2b[idx] = (short)f2bf(v);
  } else {
    for (int q = threadIdx.x; q < 3200; q += 256) {
      const int pos = q >> 7;
      const int r = q & 127;
      const int o = r >> 2, cv = r & 3;
      const int I = pos / 5, J = pos % 5;
      b2r[q] = b2[o * 121 + (2 * I + (cv >> 1)) * 11 + 2 * J + (cv & 1)];
    }
  }
}

// ---------------------------------------------------------------------------
// LC1 + ReLU + pool (fp32 math).  xT (784,N) -> h1B (169, N, 16c) bf16.
// block 256 = 4 og (4 o, wave-uniform) x 64 nl (4 n); grid (16 nt, 169 pos)
__global__ __launch_bounds__(256, 3) void k_lc1(const float* __restrict__ xT,
                                                const float* __restrict__ w1,
                                                const float* __restrict__ b1,
                                                short* __restrict__ h1b) {
  __shared__ __align__(16) float sw[640];   // [o16][36] + bias at 576
  __shared__ unsigned short ush[256 * 20];  // [n256][c16 pad20] bf16
  const int pos = blockIdx.y;
  const int i = pos / 13, j = pos % 13;
  const int tid = threadIdx.x;
  const int og = tid >> 6, nl = tid & 63;
  const int o0 = og * 4;
  const int n = blockIdx.x * 256 + nl * 4;

  for (int idx = tid; idx < 640; idx += 256) {
    float v;
    if (idx < 576) {
      const int o = idx / 36, t = idx % 36;
      const int cv = t / 9, k = t % 9;
      const int y = 2 * i + (cv >> 1), xx = 2 * j + (cv & 1);
      v = w1[(o * 9 + k) * 676 + y * 26 + xx];
    } else {
      const int r = idx - 576;
      const int o = r >> 2, cv = r & 3;
      v = b1[(o * 26 + 2 * i + (cv >> 1)) * 26 + 2 * j + (cv & 1)];
    }
    sw[idx] = v;
  }
  __syncthreads();

  float p[16][4];
  #pragma unroll
  for (int r = 0; r < 4; r++)
    #pragma unroll
    for (int cc = 0; cc < 4; cc++) {
      const float4 v = *reinterpret_cast<const float4*>(
          &xT[((2 * i + r) * 28 + (2 * j + cc)) * NB + n]);
      p[r * 4 + cc][0] = v.x; p[r * 4 + cc][1] = v.y;
      p[r * 4 + cc][2] = v.z; p[r * 4 + cc][3] = v.w;
    }

  #pragma unroll
  for (int ot = 0; ot < 4; ot++) {
    const int o = o0 + ot;
    float wf[36];
    const float4* wp = reinterpret_cast<const float4*>(&sw[o * 36]);
    #pragma unroll
    for (int q = 0; q < 9; q++) {
      const float4 v = wp[q];
      wf[4 * q] = v.x; wf[4 * q + 1] = v.y;
      wf[4 * q + 2] = v.z; wf[4 * q + 3] = v.w;
    }
    float s[4][4];
    #pragma unroll
    for (int cv = 0; cv < 4; cv++)
      #pragma unroll
      for (int e = 0; e < 4; e++) s[cv][e] = 0.f;
    #pragma unroll
    for (int cv = 0; cv < 4; cv++) {
      const int dy = cv >> 1, dx = cv & 1;
      #pragma unroll
      for (int k = 0; k < 9; k++) {
        const float wv = wf[cv * 9 + k];
        #pragma unroll
        for (int e = 0; e < 4; e++)
          s[cv][e] += wv * p[(dy + k / 3) * 4 + (dx + k % 3)][e];
      }
    }
    #pragma unroll
    for (int e = 0; e < 4; e++) {
      float best = -1e30f;
      #pragma unroll
      for (int cv = 0; cv < 4; cv++)
        best = fmaxf(best, s[cv][e] + sw[576 + o * 4 + cv]);
      ush[(nl * 4 + e) * 20 + o] = f2bf(fmaxf(best, 0.f));
    }
  }
  __syncthreads();

  // readback: thread t = local n, 16 c contiguous -> global c-minor bf16
  const int gn = blockIdx.x * 256 + tid;
  short* dst = h1b + (pos * 4096 + gn) * 16;
  const unsigned short* src = ush + tid * 20;
  *reinterpret_cast<s4v*>(dst)      = *reinterpret_cast<const s4v*>(src);
  *reinterpret_cast<s4v*>(dst + 4)  = *reinterpret_cast<const s4v*>(src + 4);
  *reinterpret_cast<s4v*>(dst + 8)  = *reinterpret_cast<const s4v*>(src + 8);
  *reinterpret_cast<s4v*>(dst + 12) = *reinterpret_cast<const s4v*>(src + 12);
}

// ---------------------------------------------------------------------------
// LC2 via bf16 MFMA 16x16x32.  h1B (169,N,16c) -> h2 (800,N) fp32.
// K=256 = (py,px,c) over the 4x4 window; cv selected by zero-padded weights
// (A-frags shared by all 4 cv).  No LDS, no barriers - pure VMEM+MFMA.
// block 256 = 4 waves: wave=(wm,ot); each wave: 2 m-tiles x 16 o x 4 cv.
// grid (64 nt of 64 n, 25 pos).
__global__ __launch_bounds__(256, 4) void k_lc2(const short* __restrict__ h1b,
                                                const short* __restrict__ w2b,
                                                const float* __restrict__ b2r,
                                                float* __restrict__ h2) {
  const int pos = blockIdx.y;
  const int I = pos / 5, J = pos % 5;
  const int tid = threadIdx.x;
  const int l = tid & 63;
  const int wave = tid >> 6;
  const int wm = wave >> 1, ot = wave & 1;
  const int n0 = blockIdx.x * 64;
  const int kg = l >> 4;       // k-group 0..3
  const int lm = l & 15;
  const int c0 = (kg & 1) * 8;
  const int whalf = kg >> 1;   // window-pos half within the 32-k step

  f4v acc[2][4];
  #pragma unroll
  for (int a = 0; a < 2; a++)
    #pragma unroll
    for (int cv = 0; cv < 4; cv++)
      acc[a][cv] = (f4v){0.f, 0.f, 0.f, 0.f};

  #pragma unroll
  for (int s = 0; s < 8; s++) {
    const int wdw = s * 2 + whalf;          // window pos 0..15 = py*4+px
    const int py = wdw >> 2, px = wdw & 3;
    const int p = (2 * I + py) * 13 + (2 * J + px);
    const int abase = (p * 4096 + n0 + wm * 32 + lm) * 16 + c0;
    const s8v a0 = *reinterpret_cast<const s8v*>(h1b + abase);
    const s8v a1 = *reinterpret_cast<const s8v*>(h1b + abase + 16 * 16);
    #pragma unroll
    for (int cv = 0; cv < 4; cv++) {
      const s8v bf = *reinterpret_cast<const s8v*>(
          w2b + ((((pos * 4 + cv) * 8 + s) * 2 + ot) * 64 + l) * 8);
      acc[0][cv] =
          __builtin_amdgcn_mfma_f32_16x16x32_bf16(a0, bf, acc[0][cv], 0, 0, 0);
      acc[1][cv] =
          __builtin_amdgcn_mfma_f32_16x16x32_bf16(a1, bf, acc[1][cv], 0, 0, 0);
    }
  }

  // epilogue: D row=(kg*4+reg)=n, col=lm=o.  max over cv + bias, relu.
  const int o = ot * 16 + lm;
  const float4 bias = *reinterpret_cast<const float4*>(b2r + (pos * 32 + o) * 4);
  const int ko = (o * 5 + I) * 5 + J;
  #pragma unroll
  for (int a = 0; a < 2; a++) {
    const int nb = n0 + wm * 32 + a * 16 + kg * 4;
    float4 res;
    res.x = fmaxf(0.f, fmaxf(fmaxf(acc[a][0][0] + bias.x, acc[a][1][0] + bias.y),
                             fmaxf(acc[a][2][0] + bias.z, acc[a][3][0] + bias.w)));
    res.y = fmaxf(0.f, fmaxf(fmaxf(acc[a][0][1] + bias.x, acc[a][1][1] + bias.y),
                             fmaxf(acc[a][2][1] + bias.z, acc[a][3][1] + bias.w)));
    res.z = fmaxf(0.f, fmaxf(fmaxf(acc[a][0][2] + bias.x, acc[a][1][2] + bias.y),
                             fmaxf(acc[a][2][2] + bias.z, acc[a][3][2] + bias.w)));
    res.w = fmaxf(0.f, fmaxf(fmaxf(acc[a][0][3] + bias.x, acc[a][1][3] + bias.y),
                             fmaxf(acc[a][2][3] + bias.z, acc[a][3][3] + bias.w)));
    *reinterpret_cast<float4*>(&h2[ko * NB + nb]) = res;
  }
}

// ---------------------------------------------------------------------------
// fused FC1(relu)+FC2.  h2 (800,N) -> out (N,10).  grid 512 (n-tile 8).
__global__ __launch_bounds__(256) void k_fc(const float* __restrict__ h2,
                                            const float* __restrict__ f1w,
                                            const float* __restrict__ f1b,
                                            const float* __restrict__ f2w,
                                            const float* __restrict__ f2b,
                                            float* __restrict__ out) {
  __shared__ __align__(16) float wch[2][4096];  // [kk32][j128], 16KB each
  __shared__ float sh3[128 * 9];                // padded h3 tile [j128][n8+1]
  __shared__ float swf2[128 * 12];              // fc2 weights, 12-padded
  __shared__ float sb1[128];
  const int tid = threadIdx.x;
  const int jg = tid >> 3;
  const int nl = tid & 7;
  const int n0 = blockIdx.x * 8;
  const int n = n0 + nl;

  for (int idx = tid; idx < 1536; idx += 256) {
    const int kk = idx / 12, f = idx % 12;
    swf2[idx] = (f < 10) ? f2w[kk * 10 + f] : 0.f;
  }
  if (tid < 128) sb1[tid] = f1b[tid];
  #pragma unroll
  for (int r = 0; r < 4; r++) {
    const int idx = tid + 256 * r;
    *reinterpret_cast<float4*>(&wch[0][idx * 4]) =
        *reinterpret_cast<const float4*>(&f1w[idx * 4]);
  }
  __syncthreads();

  float acc[4];
  #pragma unroll
  for (int jj = 0; jj < 4; jj++) acc[jj] = 0.f;

  for (int ch = 0; ch < 25; ch++) {
    const int b = ch & 1;
    const int chn = (ch < 24) ? ch + 1 : 24;
    float4 wpre[4];
    #pragma unroll
    for (int r = 0; r < 4; r++)
      wpre[r] = *reinterpret_cast<const float4*>(
          &f1w[chn * 4096 + (tid + 256 * r) * 4]);
    float av[32];
    #pragma unroll
    for (int kk = 0; kk < 32; kk++) av[kk] = h2[(ch * 32 + kk) * NB + n];
    #pragma unroll
    for (int kk = 0; kk < 32; kk++) {
      const float4 v =
          *reinterpret_cast<const float4*>(&wch[b][kk * 128 + jg * 4]);
      acc[0] += av[kk] * v.x; acc[1] += av[kk] * v.y;
      acc[2] += av[kk] * v.z; acc[3] += av[kk] * v.w;
    }
    #pragma unroll
    for (int r = 0; r < 4; r++)
      *reinterpret_cast<float4*>(&wch[b ^ 1][(tid + 256 * r) * 4]) = wpre[r];
    __syncthreads();
  }

  #pragma unroll
  for (int jj = 0; jj < 4; jj++) {
    const int j = jg * 4 + jj;
    sh3[j * 9 + nl] = fmaxf(acc[jj] + sb1[j], 0.f);
  }
  __syncthreads();
  if (tid < 80) {
    const int oo = tid >> 3;
    const int nn = tid & 7;
    float s = f2b[oo];
    for (int j = 0; j < 128; j++)
      s += sh3[j * 9 + nn] * swf2[j * 12 + oo];
    out[(n0 + nn) * 10 + oo] = s;
  }
}

// ---------------------------------------------------------------------------
extern "C" void kernel_launch(void* const* d_in, const int* in_sizes, int n_in,
                              void* d_out, int out_size, void* d_ws,
                              size_t ws_size, hipStream_t stream) {
  const float* x   = (const float*)d_in[0];
  const float* w1  = (const float*)d_in[1];
  const float* b1  = (const float*)d_in[2];
  const float* w2  = (const float*)d_in[3];
  const float* b2  = (const float*)d_in[4];
  const float* f1w = (const float*)d_in[5];
  const float* f1b = (const float*)d_in[6];
  const float* f2w = (const float*)d_in[7];
  const float* f2b = (const float*)d_in[8];
  float* out = (float*)d_out;
  char* ws = (char*)d_ws;
  float* xT  = (float*)(ws + XT_OFF);
  short* h1b = (short*)(ws + H1B_OFF);
  float* h2  = (float*)(ws + H2_OFF);
  short* w2b = (short*)(ws + W2B_OFF);
  float* b2r = (float*)(ws + B2R_OFF);

  k_prep<<<6401, 256, 0, stream>>>(x, w2, b2, xT, w2b, b2r);
  k_lc1<<<dim3(16, 169), 256, 0, stream>>>(xT, w1, b1, h1b);
  k_lc2<<<dim3(64, 25), 256, 0, stream>>>(h1b, w2b, b2r, h2);
  k_fc<<<512, 256, 0, stream>>>(h2, f1w, f1b, f2w, f2b, out);
}

// Round 8
// 153.546 us; speedup vs baseline: 1.7837x; 1.2579x over previous
//
#include <hip/hip_runtime.h>

#define NB 4096

typedef __attribute__((ext_vector_type(8))) short s8v;   // 8 bf16 (4 VGPR)
typedef __attribute__((ext_vector_type(4))) short s4v;   // 4 bf16
typedef __attribute__((ext_vector_type(4))) float f4v;   // MFMA acc

// workspace layout (bytes, 16B-aligned)
#define XB_OFF  0u           // 784*4096*2 bf16     =  6,422,528
#define H1B_OFF 6422528u     // 169*4096*16*2 bf16  = 22,151,168
#define H2_OFF  28573696u    // 800*4096*4          = 13,107,200
#define W2B_OFF 41680896u    // 25*4*8*2*64*8*2     =  1,638,400
#define B2R_OFF 43319296u    // 25*32*4*4           =     12,800
#define W1B_OFF 43332096u    // 169*4*64*8*2        =    692,224
#define B1R_OFF 44024320u    // 169*16*4*4          =     43,264
// end 44,067,584

__device__ __forceinline__ unsigned short f2bf(float f) {
  unsigned int u = __builtin_bit_cast(unsigned int, f);
  u += 0x7fffu + ((u >> 16) & 1u);
  return (unsigned short)(u >> 16);
}

// ---------------------------------------------------------------------------
// prep:
//  [0,3200)      x (4096,784) f32 -> xB (784,4096) bf16
//  [3200,4552)   w1 -> w1b  [pos169][cv4][lane64][t8]  (B-frag, K=16 window,
//                k=(l>>4)*8+t, o=l&15, zero outside cv 3x3 / k>=16)
//  [4552,4595)   b1 -> b1r  [pos169][o16][cv4] f32
//  [4595,7795)   w2 -> w2b  [pos25][cv4][s8][ot2][lane64][t8] (as R7)
//  7795          b2 -> b2r  [pos25][o32][cv4] f32
__global__ __launch_bounds__(256) void k_prep(const float* __restrict__ x,
                                              const float* __restrict__ w1,
                                              const float* __restrict__ b1,
                                              const float* __restrict__ w2,
                                              const float* __restrict__ b2,
                                              short* __restrict__ xB,
                                              short* __restrict__ w1b,
                                              float* __restrict__ b1r,
                                              short* __restrict__ w2b,
                                              float* __restrict__ b2r) {
  const int bx = blockIdx.x;
  if (bx < 3200) {
    __shared__ float t[32][33];
    const int c0 = (bx % 25) * 32;
    const int n0 = (bx / 25) * 32;
    const int tx = threadIdx.x & 31, ty = threadIdx.x >> 5;
    #pragma unroll
    for (int i = 0; i < 32; i += 8) {
      const int c = c0 + tx;
      if (c < 784) t[ty + i][tx] = x[(n0 + ty + i) * 784 + c];
    }
    __syncthreads();
    #pragma unroll
    for (int i = 0; i < 32; i += 8) {
      const int c = c0 + ty + i;
      if (c < 784) xB[c * NB + n0 + tx] = (short)f2bf(t[tx][ty + i]);
    }
  } else if (bx < 4552) {
    const int idx = (bx - 3200) * 256 + threadIdx.x;  // 346,112 elems
    const int t = idx & 7;
    const int l = (idx >> 3) & 63;
    const int cv = (idx >> 9) & 3;
    const int pos = idx >> 11;
    const int k = (l >> 4) * 8 + t;
    const int o = l & 15;
    const int i = pos / 13, j = pos % 13;
    const int dy = cv >> 1, dx = cv & 1;
    float v = 0.f;
    if (k < 16) {
      const int py = k >> 2, px = k & 3;
      const int ky = py - dy, kx = px - dx;
      if (ky >= 0 && ky < 3 && kx >= 0 && kx < 3)
        v = w1[(o * 9 + ky * 3 + kx) * 676 + (2 * i + dy) * 26 + 2 * j + dx];
    }
    w1b[idx] = (short)f2bf(v);
  } else if (bx < 4595) {
    const int idx = (bx - 4552) * 256 + threadIdx.x;  // 10,816 elems
    if (idx < 10816) {
      const int cv = idx & 3;
      const int o = (idx >> 2) & 15;
      const int pos = idx >> 6;
      const int i = pos / 13, j = pos % 13;
      b1r[idx] =
          b1[(o * 26 + 2 * i + (cv >> 1)) * 26 + 2 * j + (cv & 1)];
    }
  } else if (bx < 7795) {
    const int idx = (bx - 4595) * 256 + threadIdx.x;  // 819,200 elems
    const int t = idx & 7;
    const int l = (idx >> 3) & 63;
    const int ot = (idx >> 9) & 1;
    const int s = (idx >> 10) & 7;
    const int cv = (idx >> 13) & 3;
    const int pos = idx >> 15;
    const int k = s * 32 + (l >> 4) * 8 + t;
    const int o = ot * 16 + (l & 15);
    const int w = k >> 4, c = k & 15;
    const int py = w >> 2, px = w & 3;
    const int dy = cv >> 1, dx = cv & 1;
    const int ky = py - dy, kx = px - dx;
    const int I = pos / 5, J = pos % 5;
    float v = 0.f;
    if (ky >= 0 && ky < 3 && kx >= 0 && kx < 3)
      v = w2[((o * 16 + c) * 9 + ky * 3 + kx) * 121 +
             (2 * I + dy) * 11 + (2 * J + dx)];
    w2b[idx] = (short)f2bf(v);
  } else {
    for (int q = threadIdx.x; q < 3200; q += 256) {
      const int pos = q >> 7;
      const int r = q & 127;
      const int o = r >> 2, cv = r & 3;
      const int I = pos / 5, J = pos % 5;
      b2r[q] = b2[o * 121 + (2 * I + (cv >> 1)) * 11 + 2 * J + (cv & 1)];
    }
  }
}

// ---------------------------------------------------------------------------
// LC1 via bf16 MFMA 16x16x32 (K=16 real + 16 zero).  xB (784,N) bf16 ->
// h1B (169,N,16c) bf16.  k=(py,px) over 4x4 window; cv via zero-padded B.
// No LDS, no barriers.  block 256 = 4 waves; wave = 4 m-tiles of 16 n.
// grid (16 nt of 256 n, 169 pos).
__global__ __launch_bounds__(256, 3) void k_lc1(const short* __restrict__ xB,
                                                const short* __restrict__ w1b,
                                                const float* __restrict__ b1r,
                                                short* __restrict__ h1b) {
  const int pos = blockIdx.y;
  const int i = pos / 13, j = pos % 13;
  const int tid = threadIdx.x;
  const int l = tid & 63;
  const int wv = tid >> 6;
  const int lm = l & 15, kg = l >> 4;
  const int n0 = blockIdx.x * 256 + wv * 64;

  // B frags (one 16B load per cv) + bias (o = lm)
  s8v bf[4];
  #pragma unroll
  for (int cv = 0; cv < 4; cv++)
    bf[cv] = *reinterpret_cast<const s8v*>(w1b + ((pos * 4 + cv) * 64 + l) * 8);
  const float4 bias = *reinterpret_cast<const float4*>(b1r + (pos * 16 + lm) * 4);

  f4v acc[4][4];
  #pragma unroll
  for (int a = 0; a < 4; a++)
    #pragma unroll
    for (int cv = 0; cv < 4; cv++) acc[a][cv] = (f4v){0.f, 0.f, 0.f, 0.f};

  #pragma unroll
  for (int a = 0; a < 4; a++) {
    const int n = n0 + a * 16 + lm;
    s8v av = (s8v){0, 0, 0, 0, 0, 0, 0, 0};
    if (kg < 2) {
      #pragma unroll
      for (int t = 0; t < 8; t++) {
        const int k = kg * 8 + t;
        const int row = (2 * i + (k >> 2)) * 28 + 2 * j + (k & 3);
        av[t] = xB[row * NB + n];
      }
    }
    #pragma unroll
    for (int cv = 0; cv < 4; cv++)
      acc[a][cv] =
          __builtin_amdgcn_mfma_f32_16x16x32_bf16(av, bf[cv], acc[a][cv], 0, 0, 0);
  }

  // epilogue: D row=(kg*4+reg)=n-offset, col=lm=o.  max over cv + bias, relu.
  #pragma unroll
  for (int a = 0; a < 4; a++) {
    #pragma unroll
    for (int reg = 0; reg < 4; reg++) {
      const int n = n0 + a * 16 + kg * 4 + reg;
      const float v =
          fmaxf(fmaxf(acc[a][0][reg] + bias.x, acc[a][1][reg] + bias.y),
                fmaxf(acc[a][2][reg] + bias.z, acc[a][3][reg] + bias.w));
      h1b[(pos * 4096 + n) * 16 + lm] = (short)f2bf(fmaxf(v, 0.f));
    }
  }
}

// ---------------------------------------------------------------------------
// LC2 via bf16 MFMA 16x16x32 (unchanged from R7).  h1B -> h2 (800,N) fp32.
__global__ __launch_bounds__(256, 4) void k_lc2(const short* __restrict__ h1b,
                                                const short* __restrict__ w2b,
                                                const float* __restrict__ b2r,
                                                float* __restrict__ h2) {
  const int pos = blockIdx.y;
  const int I = pos / 5, J = pos % 5;
  const int tid = threadIdx.x;
  const int l = tid & 63;
  const int wave = tid >> 6;
  const int wm = wave >> 1, ot = wave & 1;
  const int n0 = blockIdx.x * 64;
  const int kg = l >> 4;
  const int lm = l & 15;
  const int c0 = (kg & 1) * 8;
  const int whalf = kg >> 1;

  f4v acc[2][4];
  #pragma unroll
  for (int a = 0; a < 2; a++)
    #pragma unroll
    for (int cv = 0; cv < 4; cv++)
      acc[a][cv] = (f4v){0.f, 0.f, 0.f, 0.f};

  #pragma unroll
  for (int s = 0; s < 8; s++) {
    const int wdw = s * 2 + whalf;
    const int py = wdw >> 2, px = wdw & 3;
    const int p = (2 * I + py) * 13 + (2 * J + px);
    const int abase = (p * 4096 + n0 + wm * 32 + lm) * 16 + c0;
    const s8v a0 = *reinterpret_cast<const s8v*>(h1b + abase);
    const s8v a1 = *reinterpret_cast<const s8v*>(h1b + abase + 16 * 16);
    #pragma unroll
    for (int cv = 0; cv < 4; cv++) {
      const s8v bf = *reinterpret_cast<const s8v*>(
          w2b + ((((pos * 4 + cv) * 8 + s) * 2 + ot) * 64 + l) * 8);
      acc[0][cv] =
          __builtin_amdgcn_mfma_f32_16x16x32_bf16(a0, bf, acc[0][cv], 0, 0, 0);
      acc[1][cv] =
          __builtin_amdgcn_mfma_f32_16x16x32_bf16(a1, bf, acc[1][cv], 0, 0, 0);
    }
  }

  const int o = ot * 16 + lm;
  const float4 bias = *reinterpret_cast<const float4*>(b2r + (pos * 32 + o) * 4);
  const int ko = (o * 5 + I) * 5 + J;
  #pragma unroll
  for (int a = 0; a < 2; a++) {
    const int nb = n0 + wm * 32 + a * 16 + kg * 4;
    float4 res;
    res.x = fmaxf(0.f, fmaxf(fmaxf(acc[a][0][0] + bias.x, acc[a][1][0] + bias.y),
                             fmaxf(acc[a][2][0] + bias.z, acc[a][3][0] + bias.w)));
    res.y = fmaxf(0.f, fmaxf(fmaxf(acc[a][0][1] + bias.x, acc[a][1][1] + bias.y),
                             fmaxf(acc[a][2][1] + bias.z, acc[a][3][1] + bias.w)));
    res.z = fmaxf(0.f, fmaxf(fmaxf(acc[a][0][2] + bias.x, acc[a][1][2] + bias.y),
                             fmaxf(acc[a][2][2] + bias.z, acc[a][3][2] + bias.w)));
    res.w = fmaxf(0.f, fmaxf(fmaxf(acc[a][0][3] + bias.x, acc[a][1][3] + bias.y),
                             fmaxf(acc[a][2][3] + bias.z, acc[a][3][3] + bias.w)));
    *reinterpret_cast<float4*>(&h2[ko * NB + nb]) = res;
  }
}

// ---------------------------------------------------------------------------
// fused FC1(relu)+FC2.  h2 (800,N) -> out (N,10).  grid 512 (n-tile 8).
__global__ __launch_bounds__(256) void k_fc(const float* __restrict__ h2,
                                            const float* __restrict__ f1w,
                                            const float* __restrict__ f1b,
                                            const float* __restrict__ f2w,
                                            const float* __restrict__ f2b,
                                            float* __restrict__ out) {
  __shared__ __align__(16) float wch[2][4096];  // [kk32][j128], 16KB each
  __shared__ float sh3[128 * 9];                // padded h3 tile [j128][n8+1]
  __shared__ float swf2[128 * 12];              // fc2 weights, 12-padded
  __shared__ float sb1[128];
  const int tid = threadIdx.x;
  const int jg = tid >> 3;
  const int nl = tid & 7;
  const int n0 = blockIdx.x * 8;
  const int n = n0 + nl;

  for (int idx = tid; idx < 1536; idx += 256) {
    const int kk = idx / 12, f = idx % 12;
    swf2[idx] = (f < 10) ? f2w[kk * 10 + f] : 0.f;
  }
  if (tid < 128) sb1[tid] = f1b[tid];
  #pragma unroll
  for (int r = 0; r < 4; r++) {
    const int idx = tid + 256 * r;
    *reinterpret_cast<float4*>(&wch[0][idx * 4]) =
        *reinterpret_cast<const float4*>(&f1w[idx * 4]);
  }
  __syncthreads();

  float acc[4];
  #pragma unroll
  for (int jj = 0; jj < 4; jj++) acc[jj] = 0.f;

  for (int ch = 0; ch < 25; ch++) {
    const int b = ch & 1;
    const int chn = (ch < 24) ? ch + 1 : 24;
    float4 wpre[4];
    #pragma unroll
    for (int r = 0; r < 4; r++)
      wpre[r] = *reinterpret_cast<const float4*>(
          &f1w[chn * 4096 + (tid + 256 * r) * 4]);
    float av[32];
    #pragma unroll
    for (int kk = 0; kk < 32; kk++) av[kk] = h2[(ch * 32 + kk) * NB + n];
    #pragma unroll
    for (int kk = 0; kk < 32; kk++) {
      const float4 v =
          *reinterpret_cast<const float4*>(&wch[b][kk * 128 + jg * 4]);
      acc[0] += av[kk] * v.x; acc[1] += av[kk] * v.y;
      acc[2] += av[kk] * v.z; acc[3] += av[kk] * v.w;
    }
    #pragma unroll
    for (int r = 0; r < 4; r++)
      *reinterpret_cast<float4*>(&wch[b ^ 1][(tid + 256 * r) * 4]) = wpre[r];
    __syncthreads();
  }

  #pragma unroll
  for (int jj = 0; jj < 4; jj++) {
    const int j = jg * 4 + jj;
    sh3[j * 9 + nl] = fmaxf(acc[jj] + sb1[j], 0.f);
  }
  __syncthreads();
  if (tid < 80) {
    const int oo = tid >> 3;
    const int nn = tid & 7;
    float s = f2b[oo];
    for (int j = 0; j < 128; j++)
      s += sh3[j * 9 + nn] * swf2[j * 12 + oo];
    out[(n0 + nn) * 10 + oo] = s;
  }
}

// ---------------------------------------------------------------------------
extern "C" void kernel_launch(void* const* d_in, const int* in_sizes, int n_in,
                              void* d_out, int out_size, void* d_ws,
                              size_t ws_size, hipStream_t stream) {
  const float* x   = (const float*)d_in[0];
  const float* w1  = (const float*)d_in[1];
  const float* b1  = (const float*)d_in[2];
  const float* w2  = (const float*)d_in[3];
  const float* b2  = (const float*)d_in[4];
  const float* f1w = (const float*)d_in[5];
  const float* f1b = (const float*)d_in[6];
  const float* f2w = (const float*)d_in[7];
  const float* f2b = (const float*)d_in[8];
  float* out = (float*)d_out;
  char* ws = (char*)d_ws;
  short* xB  = (short*)(ws + XB_OFF);
  short* h1b = (short*)(ws + H1B_OFF);
  float* h2  = (float*)(ws + H2_OFF);
  short* w2b = (short*)(ws + W2B_OFF);
  float* b2r = (float*)(ws + B2R_OFF);
  short* w1b = (short*)(ws + W1B_OFF);
  float* b1r = (float*)(ws + B1R_OFF);

  k_prep<<<7796, 256, 0, stream>>>(x, w1, b1, w2, b2, xB, w1b, b1r, w2b, b2r);
  k_lc1<<<dim3(16, 169), 256, 0, stream>>>(xB, w1b, b1r, h1b);
  k_lc2<<<dim3(64, 25), 256, 0, stream>>>(h1b, w2b, b2r, h2);
  k_fc<<<512, 256, 0, stream>>>(h2, f1w, f1b, f2w, f2b, out);
}

// Round 9
// 124.285 us; speedup vs baseline: 2.2037x; 1.2354x over previous
//
#include <hip/hip_runtime.h>

#define NB 4096

typedef __attribute__((ext_vector_type(8))) short s8v;   // 8 bf16 (4 VGPR)
typedef __attribute__((ext_vector_type(4))) float f4v;   // MFMA acc

// workspace layout (bytes, 16B-aligned)
#define XB_OFF  0u           // 784*4096*2 bf16     =  6,422,528
#define H1B_OFF 6422528u     // 169*4096*16*2 bf16  = 22,151,168
#define H2B_OFF 28573696u    // 25*4096*32*2 bf16   =  6,553,600
#define W2B_OFF 35127296u    // 25*4*8*2*64*8*2     =  1,638,400
#define B2R_OFF 36765696u    // 25*32*4*4           =     12,800
#define W1B_OFF 36778496u    // 169*4*64*8*2        =    692,224
#define B1R_OFF 37470720u    // 169*16*4*4          =     43,264
#define WFB_OFF 37513984u    // 25*8*64*8*2         =    204,800
// end 37,718,784

__device__ __forceinline__ unsigned short f2bf(float f) {
  unsigned int u = __builtin_bit_cast(unsigned int, f);
  u += 0x7fffu + ((u >> 16) & 1u);
  return (unsigned short)(u >> 16);
}

// ---------------------------------------------------------------------------
// prep:
//  [0,3200)      x (4096,784) f32 -> xB (784,4096) bf16
//  [3200,4552)   w1 -> w1b  [pos169][cv4][lane64][t8]  (lc1 B-frags, K=16)
//  [4552,4595)   b1 -> b1r  [pos169][o16][cv4] f32
//  [4595,7795)   w2 -> w2b  [pos25][cv4][s8][ot2][lane64][t8] (lc2 B-frags)
//  7795          b2 -> b2r  [pos25][o32][cv4] f32
//  [7796,8196)   f1w -> wfb [s25][jt8][lane64][t8]  (fc1 B-frags, K-permuted
//                k' = pos*32 + o, i.e. original k = o*25 + s, j = jt*16+lm)
__global__ __launch_bounds__(256) void k_prep(const float* __restrict__ x,
                                              const float* __restrict__ w1,
                                              const float* __restrict__ b1,
                                              const float* __restrict__ w2,
                                              const float* __restrict__ b2,
                                              const float* __restrict__ f1w,
                                              short* __restrict__ xB,
                                              short* __restrict__ w1b,
                                              float* __restrict__ b1r,
                                              short* __restrict__ w2b,
                                              float* __restrict__ b2r,
                                              short* __restrict__ wfb) {
  const int bx = blockIdx.x;
  if (bx < 3200) {
    __shared__ float t[32][33];
    const int c0 = (bx % 25) * 32;
    const int n0 = (bx / 25) * 32;
    const int tx = threadIdx.x & 31, ty = threadIdx.x >> 5;
    #pragma unroll
    for (int i = 0; i < 32; i += 8) {
      const int c = c0 + tx;
      if (c < 784) t[ty + i][tx] = x[(n0 + ty + i) * 784 + c];
    }
    __syncthreads();
    #pragma unroll
    for (int i = 0; i < 32; i += 8) {
      const int c = c0 + ty + i;
      if (c < 784) xB[c * NB + n0 + tx] = (short)f2bf(t[tx][ty + i]);
    }
  } else if (bx < 4552) {
    const int idx = (bx - 3200) * 256 + threadIdx.x;  // 346,112 elems
    const int t = idx & 7;
    const int l = (idx >> 3) & 63;
    const int cv = (idx >> 9) & 3;
    const int pos = idx >> 11;
    const int k = (l >> 4) * 8 + t;
    const int o = l & 15;
    const int i = pos / 13, j = pos % 13;
    const int dy = cv >> 1, dx = cv & 1;
    float v = 0.f;
    if (k < 16) {
      const int py = k >> 2, px = k & 3;
      const int ky = py - dy, kx = px - dx;
      if (ky >= 0 && ky < 3 && kx >= 0 && kx < 3)
        v = w1[(o * 9 + ky * 3 + kx) * 676 + (2 * i + dy) * 26 + 2 * j + dx];
    }
    w1b[idx] = (short)f2bf(v);
  } else if (bx < 4595) {
    const int idx = (bx - 4552) * 256 + threadIdx.x;  // 10,816 elems
    if (idx < 10816) {
      const int cv = idx & 3;
      const int o = (idx >> 2) & 15;
      const int pos = idx >> 6;
      const int i = pos / 13, j = pos % 13;
      b1r[idx] = b1[(o * 26 + 2 * i + (cv >> 1)) * 26 + 2 * j + (cv & 1)];
    }
  } else if (bx < 7795) {
    const int idx = (bx - 4595) * 256 + threadIdx.x;  // 819,200 elems
    const int t = idx & 7;
    const int l = (idx >> 3) & 63;
    const int ot = (idx >> 9) & 1;
    const int s = (idx >> 10) & 7;
    const int cv = (idx >> 13) & 3;
    const int pos = idx >> 15;
    const int k = s * 32 + (l >> 4) * 8 + t;
    const int o = ot * 16 + (l & 15);
    const int w = k >> 4, c = k & 15;
    const int py = w >> 2, px = w & 3;
    const int dy = cv >> 1, dx = cv & 1;
    const int ky = py - dy, kx = px - dx;
    const int I = pos / 5, J = pos % 5;
    float v = 0.f;
    if (ky >= 0 && ky < 3 && kx >= 0 && kx < 3)
      v = w2[((o * 16 + c) * 9 + ky * 3 + kx) * 121 +
             (2 * I + dy) * 11 + (2 * J + dx)];
    w2b[idx] = (short)f2bf(v);
  } else if (bx == 7795) {
    for (int q = threadIdx.x; q < 3200; q += 256) {
      const int pos = q >> 7;
      const int r = q & 127;
      const int o = r >> 2, cv = r & 3;
      const int I = pos / 5, J = pos % 5;
      b2r[q] = b2[o * 121 + (2 * I + (cv >> 1)) * 11 + 2 * J + (cv & 1)];
    }
  } else {
    const int idx = (bx - 7796) * 256 + threadIdx.x;  // 102,400 elems
    const int t = idx & 7;
    const int l = (idx >> 3) & 63;
    const int jt = (idx >> 9) & 7;
    const int s = idx >> 12;
    const int o = (l >> 4) * 8 + t;
    const int j = jt * 16 + (l & 15);
    wfb[idx] = (short)f2bf(f1w[(o * 25 + s) * 128 + j]);
  }
}

// ---------------------------------------------------------------------------
// LC1 via bf16 MFMA 16x16x32 (K=16 real + 16 zero).  xB (784,N) bf16 ->
// h1B (169,N,16c) bf16.  No LDS, no barriers.
__global__ __launch_bounds__(256, 3) void k_lc1(const short* __restrict__ xB,
                                                const short* __restrict__ w1b,
                                                const float* __restrict__ b1r,
                                                short* __restrict__ h1b) {
  const int pos = blockIdx.y;
  const int i = pos / 13, j = pos % 13;
  const int tid = threadIdx.x;
  const int l = tid & 63;
  const int wv = tid >> 6;
  const int lm = l & 15, kg = l >> 4;
  const int n0 = blockIdx.x * 256 + wv * 64;

  s8v bf[4];
  #pragma unroll
  for (int cv = 0; cv < 4; cv++)
    bf[cv] = *reinterpret_cast<const s8v*>(w1b + ((pos * 4 + cv) * 64 + l) * 8);
  const float4 bias = *reinterpret_cast<const float4*>(b1r + (pos * 16 + lm) * 4);

  f4v acc[4][4];
  #pragma unroll
  for (int a = 0; a < 4; a++)
    #pragma unroll
    for (int cv = 0; cv < 4; cv++) acc[a][cv] = (f4v){0.f, 0.f, 0.f, 0.f};

  #pragma unroll
  for (int a = 0; a < 4; a++) {
    const int n = n0 + a * 16 + lm;
    s8v av = (s8v){0, 0, 0, 0, 0, 0, 0, 0};
    if (kg < 2) {
      #pragma unroll
      for (int t = 0; t < 8; t++) {
        const int k = kg * 8 + t;
        const int row = (2 * i + (k >> 2)) * 28 + 2 * j + (k & 3);
        av[t] = xB[row * NB + n];
      }
    }
    #pragma unroll
    for (int cv = 0; cv < 4; cv++)
      acc[a][cv] =
          __builtin_amdgcn_mfma_f32_16x16x32_bf16(av, bf[cv], acc[a][cv], 0, 0, 0);
  }

  #pragma unroll
  for (int a = 0; a < 4; a++) {
    #pragma unroll
    for (int reg = 0; reg < 4; reg++) {
      const int n = n0 + a * 16 + kg * 4 + reg;
      const float v =
          fmaxf(fmaxf(acc[a][0][reg] + bias.x, acc[a][1][reg] + bias.y),
                fmaxf(acc[a][2][reg] + bias.z, acc[a][3][reg] + bias.w));
      h1b[(pos * 4096 + n) * 16 + lm] = (short)f2bf(fmaxf(v, 0.f));
    }
  }
}

// ---------------------------------------------------------------------------
// LC2 via bf16 MFMA 16x16x32.  h1B -> h2b [pos25][n4096][o32] bf16 (the FC
// K-permuted activation layout: one lc2 block emits a contiguous slab).
__global__ __launch_bounds__(256, 4) void k_lc2(const short* __restrict__ h1b,
                                                const short* __restrict__ w2b,
                                                const float* __restrict__ b2r,
                                                short* __restrict__ h2b) {
  const int pos = blockIdx.y;
  const int I = pos / 5, J = pos % 5;
  const int tid = threadIdx.x;
  const int l = tid & 63;
  const int wave = tid >> 6;
  const int wm = wave >> 1, ot = wave & 1;
  const int n0 = blockIdx.x * 64;
  const int kg = l >> 4;
  const int lm = l & 15;
  const int c0 = (kg & 1) * 8;
  const int whalf = kg >> 1;

  f4v acc[2][4];
  #pragma unroll
  for (int a = 0; a < 2; a++)
    #pragma unroll
    for (int cv = 0; cv < 4; cv++)
      acc[a][cv] = (f4v){0.f, 0.f, 0.f, 0.f};

  #pragma unroll
  for (int s = 0; s < 8; s++) {
    const int wdw = s * 2 + whalf;
    const int py = wdw >> 2, px = wdw & 3;
    const int p = (2 * I + py) * 13 + (2 * J + px);
    const int abase = (p * 4096 + n0 + wm * 32 + lm) * 16 + c0;
    const s8v a0 = *reinterpret_cast<const s8v*>(h1b + abase);
    const s8v a1 = *reinterpret_cast<const s8v*>(h1b + abase + 16 * 16);
    #pragma unroll
    for (int cv = 0; cv < 4; cv++) {
      const s8v bf = *reinterpret_cast<const s8v*>(
          w2b + ((((pos * 4 + cv) * 8 + s) * 2 + ot) * 64 + l) * 8);
      acc[0][cv] =
          __builtin_amdgcn_mfma_f32_16x16x32_bf16(a0, bf, acc[0][cv], 0, 0, 0);
      acc[1][cv] =
          __builtin_amdgcn_mfma_f32_16x16x32_bf16(a1, bf, acc[1][cv], 0, 0, 0);
    }
  }

  const int o = ot * 16 + lm;
  const float4 bias = *reinterpret_cast<const float4*>(b2r + (pos * 32 + o) * 4);
  #pragma unroll
  for (int a = 0; a < 2; a++) {
    const int nb = n0 + wm * 32 + a * 16 + kg * 4;
    #pragma unroll
    for (int reg = 0; reg < 4; reg++) {
      const float v =
          fmaxf(fmaxf(acc[a][0][reg] + bias.x, acc[a][1][reg] + bias.y),
                fmaxf(acc[a][2][reg] + bias.z, acc[a][3][reg] + bias.w));
      h2b[(pos * 4096 + nb + reg) * 32 + o] = (short)f2bf(fmaxf(v, 0.f));
    }
  }
}

// ---------------------------------------------------------------------------
// fused FC1(relu)+FC2 via bf16 MFMA.  h2b (K'-permuted) -> out (N,10).
// grid 256 (n-tile 16), block 256 = 4 waves; wave w covers j-tiles {2w,2w+1}.
// Main loop: fully unrolled 25 steps, no LDS, no barriers; A-load is one
// coalesced 1KB wave-load, B from L2-resident wfb.
__global__ __launch_bounds__(256) void k_fc(const short* __restrict__ h2b,
                                            const short* __restrict__ wfb,
                                            const float* __restrict__ f1b,
                                            const float* __restrict__ f2w,
                                            const float* __restrict__ f2b,
                                            float* __restrict__ out) {
  __shared__ float sh3[128 * 17];   // [j128][n16 pad17]
  __shared__ float swf2[128 * 12];  // fc2 weights, 12-padded
  __shared__ float sb1[128];
  const int tid = threadIdx.x;
  const int l = tid & 63;
  const int w = tid >> 6;
  const int lm = l & 15, kg = l >> 4;
  const int n0 = blockIdx.x * 16;
  const int jt0 = w * 2;

  for (int idx = tid; idx < 1536; idx += 256) {
    const int kk = idx / 12, f = idx % 12;
    swf2[idx] = (f < 10) ? f2w[kk * 10 + f] : 0.f;
  }
  if (tid < 128) sb1[tid] = f1b[tid];

  f4v acc0 = (f4v){0.f, 0.f, 0.f, 0.f};
  f4v acc1 = (f4v){0.f, 0.f, 0.f, 0.f};

  #pragma unroll
  for (int s = 0; s < 25; s++) {
    const s8v av = *reinterpret_cast<const s8v*>(
        h2b + (s * 4096 + n0 + lm) * 32 + kg * 8);
    const s8v b0 = *reinterpret_cast<const s8v*>(
        wfb + ((s * 8 + jt0) * 64 + l) * 8);
    const s8v b1v = *reinterpret_cast<const s8v*>(
        wfb + ((s * 8 + jt0 + 1) * 64 + l) * 8);
    acc0 = __builtin_amdgcn_mfma_f32_16x16x32_bf16(av, b0, acc0, 0, 0, 0);
    acc1 = __builtin_amdgcn_mfma_f32_16x16x32_bf16(av, b1v, acc1, 0, 0, 0);
  }
  __syncthreads();

  #pragma unroll
  for (int q = 0; q < 2; q++) {
    const f4v a = q ? acc1 : acc0;
    const int j = (jt0 + q) * 16 + lm;
    #pragma unroll
    for (int reg = 0; reg < 4; reg++)
      sh3[j * 17 + kg * 4 + reg] = fmaxf(a[reg] + sb1[j], 0.f);
  }
  __syncthreads();

  if (tid < 160) {
    const int oo = tid >> 4, nn = tid & 15;
    float s = f2b[oo];
    for (int j = 0; j < 128; j++)
      s += sh3[j * 17 + nn] * swf2[j * 12 + oo];
    out[(n0 + nn) * 10 + oo] = s;
  }
}

// ---------------------------------------------------------------------------
extern "C" void kernel_launch(void* const* d_in, const int* in_sizes, int n_in,
                              void* d_out, int out_size, void* d_ws,
                              size_t ws_size, hipStream_t stream) {
  const float* x   = (const float*)d_in[0];
  const float* w1  = (const float*)d_in[1];
  const float* b1  = (const float*)d_in[2];
  const float* w2  = (const float*)d_in[3];
  const float* b2  = (const float*)d_in[4];
  const float* f1w = (const float*)d_in[5];
  const float* f1b = (const float*)d_in[6];
  const float* f2w = (const float*)d_in[7];
  const float* f2b = (const float*)d_in[8];
  float* out = (float*)d_out;
  char* ws = (char*)d_ws;
  short* xB  = (short*)(ws + XB_OFF);
  short* h1b = (short*)(ws + H1B_OFF);
  short* h2b = (short*)(ws + H2B_OFF);
  short* w2b = (short*)(ws + W2B_OFF);
  float* b2r = (float*)(ws + B2R_OFF);
  short* w1b = (short*)(ws + W1B_OFF);
  float* b1r = (float*)(ws + B1R_OFF);
  short* wfb = (short*)(ws + WFB_OFF);

  k_prep<<<8196, 256, 0, stream>>>(x, w1, b1, w2, b2, f1w,
                                   xB, w1b, b1r, w2b, b2r, wfb);
  k_lc1<<<dim3(16, 169), 256, 0, stream>>>(xB, w1b, b1r, h1b);
  k_lc2<<<dim3(64, 25), 256, 0, stream>>>(h1b, w2b, b2r, h2b);
  k_fc<<<256, 256, 0, stream>>>(h2b, wfb, f1b, f2w, f2b, out);
}

// Round 10
// 120.256 us; speedup vs baseline: 2.2775x; 1.0335x over previous
//
#include <hip/hip_runtime.h>

#define NB 4096

typedef __attribute__((ext_vector_type(8))) short s8v;   // 8 bf16 (4 VGPR)
typedef __attribute__((ext_vector_type(4))) float f4v;   // MFMA acc

// workspace layout (bytes, 16B-aligned)
#define XB_OFF  0u           // 784*4096*2 bf16     =  6,422,528
#define H1B_OFF 6422528u     // 169*4096*16*2 bf16  = 22,151,168
#define H2B_OFF 28573696u    // 25*4096*32*2 bf16   =  6,553,600
#define W2B_OFF 35127296u    // 25*4*8*2*64*8*2     =  1,638,400
#define B2R_OFF 36765696u    // 25*32*4*4           =     12,800
#define W1B_OFF 36778496u    // 169*4*64*8*2        =    692,224
#define B1R_OFF 37470720u    // 169*16*4*4          =     43,264
#define WFB_OFF 37513984u    // 25*8*64*8*2         =    204,800
// end 37,718,784

__device__ __forceinline__ unsigned short f2bf(float f) {
  unsigned int u = __builtin_bit_cast(unsigned int, f);
  u += 0x7fffu + ((u >> 16) & 1u);
  return (unsigned short)(u >> 16);
}

// ---------------------------------------------------------------------------
// prep:
//  [0,3200)      x (4096,784) f32 -> xB (784,4096) bf16
//  [3200,4552)   w1 -> w1b  [pos169][cv4][lane64][t8]  (lc1 B-frags, K=16)
//  [4552,4595)   b1 -> b1r  [pos169][o16][cv4] f32
//  [4595,7795)   w2 -> w2b  [pos25][cv4][s8][ot2][lane64][t8] (lc2 B-frags)
//  7795          b2 -> b2r  [pos25][o32][cv4] f32
//  [7796,8196)   f1w -> wfb [s25][jt8][lane64][t8]  (fc1 B-frags, K-permuted
//                k' = pos*32 + o, i.e. original k = o*25 + s, j = jt*16+lm)
__global__ __launch_bounds__(256) void k_prep(const float* __restrict__ x,
                                              const float* __restrict__ w1,
                                              const float* __restrict__ b1,
                                              const float* __restrict__ w2,
                                              const float* __restrict__ b2,
                                              const float* __restrict__ f1w,
                                              short* __restrict__ xB,
                                              short* __restrict__ w1b,
                                              float* __restrict__ b1r,
                                              short* __restrict__ w2b,
                                              float* __restrict__ b2r,
                                              short* __restrict__ wfb) {
  const int bx = blockIdx.x;
  if (bx < 3200) {
    __shared__ float t[32][33];
    const int c0 = (bx % 25) * 32;
    const int n0 = (bx / 25) * 32;
    const int tx = threadIdx.x & 31, ty = threadIdx.x >> 5;
    #pragma unroll
    for (int i = 0; i < 32; i += 8) {
      const int c = c0 + tx;
      if (c < 784) t[ty + i][tx] = x[(n0 + ty + i) * 784 + c];
    }
    __syncthreads();
    #pragma unroll
    for (int i = 0; i < 32; i += 8) {
      const int c = c0 + ty + i;
      if (c < 784) xB[c * NB + n0 + tx] = (short)f2bf(t[tx][ty + i]);
    }
  } else if (bx < 4552) {
    const int idx = (bx - 3200) * 256 + threadIdx.x;  // 346,112 elems
    const int t = idx & 7;
    const int l = (idx >> 3) & 63;
    const int cv = (idx >> 9) & 3;
    const int pos = idx >> 11;
    const int k = (l >> 4) * 8 + t;
    const int o = l & 15;
    const int i = pos / 13, j = pos % 13;
    const int dy = cv >> 1, dx = cv & 1;
    float v = 0.f;
    if (k < 16) {
      const int py = k >> 2, px = k & 3;
      const int ky = py - dy, kx = px - dx;
      if (ky >= 0 && ky < 3 && kx >= 0 && kx < 3)
        v = w1[(o * 9 + ky * 3 + kx) * 676 + (2 * i + dy) * 26 + 2 * j + dx];
    }
    w1b[idx] = (short)f2bf(v);
  } else if (bx < 4595) {
    const int idx = (bx - 4552) * 256 + threadIdx.x;  // 10,816 elems
    if (idx < 10816) {
      const int cv = idx & 3;
      const int o = (idx >> 2) & 15;
      const int pos = idx >> 6;
      const int i = pos / 13, j = pos % 13;
      b1r[idx] = b1[(o * 26 + 2 * i + (cv >> 1)) * 26 + 2 * j + (cv & 1)];
    }
  } else if (bx < 7795) {
    const int idx = (bx - 4595) * 256 + threadIdx.x;  // 819,200 elems
    const int t = idx & 7;
    const int l = (idx >> 3) & 63;
    const int ot = (idx >> 9) & 1;
    const int s = (idx >> 10) & 7;
    const int cv = (idx >> 13) & 3;
    const int pos = idx >> 15;
    const int k = s * 32 + (l >> 4) * 8 + t;
    const int o = ot * 16 + (l & 15);
    const int w = k >> 4, c = k & 15;
    const int py = w >> 2, px = w & 3;
    const int dy = cv >> 1, dx = cv & 1;
    const int ky = py - dy, kx = px - dx;
    const int I = pos / 5, J = pos % 5;
    float v = 0.f;
    if (ky >= 0 && ky < 3 && kx >= 0 && kx < 3)
      v = w2[((o * 16 + c) * 9 + ky * 3 + kx) * 121 +
             (2 * I + dy) * 11 + (2 * J + dx)];
    w2b[idx] = (short)f2bf(v);
  } else if (bx == 7795) {
    for (int q = threadIdx.x; q < 3200; q += 256) {
      const int pos = q >> 7;
      const int r = q & 127;
      const int o = r >> 2, cv = r & 3;
      const int I = pos / 5, J = pos % 5;
      b2r[q] = b2[o * 121 + (2 * I + (cv >> 1)) * 11 + 2 * J + (cv & 1)];
    }
  } else {
    const int idx = (bx - 7796) * 256 + threadIdx.x;  // 102,400 elems
    const int t = idx & 7;
    const int l = (idx >> 3) & 63;
    const int jt = (idx >> 9) & 7;
    const int s = idx >> 12;
    const int o = (l >> 4) * 8 + t;
    const int j = jt * 16 + (l & 15);
    wfb[idx] = (short)f2bf(f1w[(o * 25 + s) * 128 + j]);
  }
}

// ---------------------------------------------------------------------------
// LC1 via bf16 MFMA 16x16x32 (K=16 real + 16 zero).  xB (784,N) bf16 ->
// h1B (169,N,16c) bf16.
// R10: LDS-staged.  (1) 16 window rows of xB staged with 2 coalesced b128
// loads/thread (replaces 32 global u16 gathers/thread with cheap ds_read_u16;
// row pitch 264 + (row>>3)*16 swizzle -> kg groups hit disjoint bank octets).
// (2) epilogue through LDS tile (pitch 24: kg offset 48dw==16 mod 32, 2-way
// only) -> 2 contiguous b128 global stores/thread (replaces 16 2B scatters).
__global__ __launch_bounds__(256, 3) void k_lc1(const short* __restrict__ xB,
                                                const short* __restrict__ w1b,
                                                const float* __restrict__ b1r,
                                                short* __restrict__ h1b) {
  __shared__ short sx[16 * 264 + 16 + 8];       // swizzled [k16][n256]
  __shared__ unsigned short ush[256 * 24];      // [n256 pitch24][o16]
  const int pos = blockIdx.y;
  const int i = pos / 13, j = pos % 13;
  const int tid = threadIdx.x;
  const int l = tid & 63;
  const int wv = tid >> 6;
  const int lm = l & 15, kg = l >> 4;
  const int n0b = blockIdx.x * 256;

  // stage 16 window rows (8KB), fully coalesced
  #pragma unroll
  for (int rr = 0; rr < 2; rr++) {
    const int idx = rr * 256 + tid;
    const int row = idx >> 5, seg = idx & 31;
    const int grow = (2 * i + (row >> 2)) * 28 + (2 * j + (row & 3));
    *reinterpret_cast<s8v*>(&sx[row * 264 + ((row >> 3) & 1) * 16 + seg * 8]) =
        *reinterpret_cast<const s8v*>(&xB[grow * NB + n0b + seg * 8]);
  }

  // B frags (one 16B load per cv) + bias (o = lm)
  s8v bf[4];
  #pragma unroll
  for (int cv = 0; cv < 4; cv++)
    bf[cv] = *reinterpret_cast<const s8v*>(w1b + ((pos * 4 + cv) * 64 + l) * 8);
  const float4 bias = *reinterpret_cast<const float4*>(b1r + (pos * 16 + lm) * 4);
  __syncthreads();

  f4v acc[4][4];
  #pragma unroll
  for (int a = 0; a < 4; a++)
    #pragma unroll
    for (int cv = 0; cv < 4; cv++) acc[a][cv] = (f4v){0.f, 0.f, 0.f, 0.f};

  #pragma unroll
  for (int a = 0; a < 4; a++) {
    const int nl = wv * 64 + a * 16 + lm;
    s8v av = (s8v){0, 0, 0, 0, 0, 0, 0, 0};
    if (kg < 2) {
      #pragma unroll
      for (int t = 0; t < 8; t++) {
        const int k = kg * 8 + t;
        av[t] = sx[k * 264 + ((k >> 3) & 1) * 16 + nl];
      }
    }
    #pragma unroll
    for (int cv = 0; cv < 4; cv++)
      acc[a][cv] =
          __builtin_amdgcn_mfma_f32_16x16x32_bf16(av, bf[cv], acc[a][cv], 0, 0, 0);
  }

  // epilogue: D row=(kg*4+reg)=n-offset, col=lm=o -> LDS tile
  #pragma unroll
  for (int a = 0; a < 4; a++) {
    #pragma unroll
    for (int reg = 0; reg < 4; reg++) {
      const int nl = wv * 64 + a * 16 + kg * 4 + reg;
      const float v =
          fmaxf(fmaxf(acc[a][0][reg] + bias.x, acc[a][1][reg] + bias.y),
                fmaxf(acc[a][2][reg] + bias.z, acc[a][3][reg] + bias.w));
      ush[nl * 24 + lm] = f2bf(fmaxf(v, 0.f));
    }
  }
  __syncthreads();

  // coalesced writeback: thread t = n, 32B contiguous
  short* dst = h1b + (pos * 4096 + n0b + tid) * 16;
  const unsigned short* src = ush + tid * 24;
  *reinterpret_cast<s8v*>(dst) = *reinterpret_cast<const s8v*>(src);
  *reinterpret_cast<s8v*>(dst + 8) = *reinterpret_cast<const s8v*>(src + 8);
}

// ---------------------------------------------------------------------------
// LC2 via bf16 MFMA 16x16x32.  h1B -> h2b [pos25][n4096][o32] bf16 (the FC
// K-permuted activation layout: one lc2 block emits a contiguous slab).
__global__ __launch_bounds__(256, 4) void k_lc2(const short* __restrict__ h1b,
                                                const short* __restrict__ w2b,
                                                const float* __restrict__ b2r,
                                                short* __restrict__ h2b) {
  const int pos = blockIdx.y;
  const int I = pos / 5, J = pos % 5;
  const int tid = threadIdx.x;
  const int l = tid & 63;
  const int wave = tid >> 6;
  const int wm = wave >> 1, ot = wave & 1;
  const int n0 = blockIdx.x * 64;
  const int kg = l >> 4;
  const int lm = l & 15;
  const int c0 = (kg & 1) * 8;
  const int whalf = kg >> 1;

  f4v acc[2][4];
  #pragma unroll
  for (int a = 0; a < 2; a++)
    #pragma unroll
    for (int cv = 0; cv < 4; cv++)
      acc[a][cv] = (f4v){0.f, 0.f, 0.f, 0.f};

  #pragma unroll
  for (int s = 0; s < 8; s++) {
    const int wdw = s * 2 + whalf;
    const int py = wdw >> 2, px = wdw & 3;
    const int p = (2 * I + py) * 13 + (2 * J + px);
    const int abase = (p * 4096 + n0 + wm * 32 + lm) * 16 + c0;
    const s8v a0 = *reinterpret_cast<const s8v*>(h1b + abase);
    const s8v a1 = *reinterpret_cast<const s8v*>(h1b + abase + 16 * 16);
    #pragma unroll
    for (int cv = 0; cv < 4; cv++) {
      const s8v bf = *reinterpret_cast<const s8v*>(
          w2b + ((((pos * 4 + cv) * 8 + s) * 2 + ot) * 64 + l) * 8);
      acc[0][cv] =
          __builtin_amdgcn_mfma_f32_16x16x32_bf16(a0, bf, acc[0][cv], 0, 0, 0);
      acc[1][cv] =
          __builtin_amdgcn_mfma_f32_16x16x32_bf16(a1, bf, acc[1][cv], 0, 0, 0);
    }
  }

  const int o = ot * 16 + lm;
  const float4 bias = *reinterpret_cast<const float4*>(b2r + (pos * 32 + o) * 4);
  #pragma unroll
  for (int a = 0; a < 2; a++) {
    const int nb = n0 + wm * 32 + a * 16 + kg * 4;
    #pragma unroll
    for (int reg = 0; reg < 4; reg++) {
      const float v =
          fmaxf(fmaxf(acc[a][0][reg] + bias.x, acc[a][1][reg] + bias.y),
                fmaxf(acc[a][2][reg] + bias.z, acc[a][3][reg] + bias.w));
      h2b[(pos * 4096 + nb + reg) * 32 + o] = (short)f2bf(fmaxf(v, 0.f));
    }
  }
}

// ---------------------------------------------------------------------------
// fused FC1(relu)+FC2 via bf16 MFMA.  h2b (K'-permuted) -> out (N,10).
// grid 256 (n-tile 16), block 256 = 4 waves; wave w covers j-tiles {2w,2w+1}.
__global__ __launch_bounds__(256) void k_fc(const short* __restrict__ h2b,
                                            const short* __restrict__ wfb,
                                            const float* __restrict__ f1b,
                                            const float* __restrict__ f2w,
                                            const float* __restrict__ f2b,
                                            float* __restrict__ out) {
  __shared__ float sh3[128 * 17];   // [j128][n16 pad17]
  __shared__ float swf2[128 * 12];  // fc2 weights, 12-padded
  __shared__ float sb1[128];
  const int tid = threadIdx.x;
  const int l = tid & 63;
  const int w = tid >> 6;
  const int lm = l & 15, kg = l >> 4;
  const int n0 = blockIdx.x * 16;
  const int jt0 = w * 2;

  for (int idx = tid; idx < 1536; idx += 256) {
    const int kk = idx / 12, f = idx % 12;
    swf2[idx] = (f < 10) ? f2w[kk * 10 + f] : 0.f;
  }
  if (tid < 128) sb1[tid] = f1b[tid];

  f4v acc0 = (f4v){0.f, 0.f, 0.f, 0.f};
  f4v acc1 = (f4v){0.f, 0.f, 0.f, 0.f};

  #pragma unroll
  for (int s = 0; s < 25; s++) {
    const s8v av = *reinterpret_cast<const s8v*>(
        h2b + (s * 4096 + n0 + lm) * 32 + kg * 8);
    const s8v b0 = *reinterpret_cast<const s8v*>(
        wfb + ((s * 8 + jt0) * 64 + l) * 8);
    const s8v b1v = *reinterpret_cast<const s8v*>(
        wfb + ((s * 8 + jt0 + 1) * 64 + l) * 8);
    acc0 = __builtin_amdgcn_mfma_f32_16x16x32_bf16(av, b0, acc0, 0, 0, 0);
    acc1 = __builtin_amdgcn_mfma_f32_16x16x32_bf16(av, b1v, acc1, 0, 0, 0);
  }
  __syncthreads();

  #pragma unroll
  for (int q = 0; q < 2; q++) {
    const f4v a = q ? acc1 : acc0;
    const int j = (jt0 + q) * 16 + lm;
    #pragma unroll
    for (int reg = 0; reg < 4; reg++)
      sh3[j * 17 + kg * 4 + reg] = fmaxf(a[reg] + sb1[j], 0.f);
  }
  __syncthreads();

  if (tid < 160) {
    const int oo = tid >> 4, nn = tid & 15;
    float s = f2b[oo];
    for (int j = 0; j < 128; j++)
      s += sh3[j * 17 + nn] * swf2[j * 12 + oo];
    out[(n0 + nn) * 10 + oo] = s;
  }
}

// ---------------------------------------------------------------------------
extern "C" void kernel_launch(void* const* d_in, const int* in_sizes, int n_in,
                              void* d_out, int out_size, void* d_ws,
                              size_t ws_size, hipStream_t stream) {
  const float* x   = (const float*)d_in[0];
  const float* w1  = (const float*)d_in[1];
  const float* b1  = (const float*)d_in[2];
  const float* w2  = (const float*)d_in[3];
  const float* b2  = (const float*)d_in[4];
  const float* f1w = (const float*)d_in[5];
  const float* f1b = (const float*)d_in[6];
  const float* f2w = (const float*)d_in[7];
  const float* f2b = (const float*)d_in[8];
  float* out = (float*)d_out;
  char* ws = (char*)d_ws;
  short* xB  = (short*)(ws + XB_OFF);
  short* h1b = (short*)(ws + H1B_OFF);
  short* h2b = (short*)(ws + H2B_OFF);
  short* w2b = (short*)(ws + W2B_OFF);
  float* b2r = (float*)(ws + B2R_OFF);
  short* w1b = (short*)(ws + W1B_OFF);
  float* b1r = (float*)(ws + B1R_OFF);
  short* wfb = (short*)(ws + WFB_OFF);

  k_prep<<<8196, 256, 0, stream>>>(x, w1, b1, w2, b2, f1w,
                                   xB, w1b, b1r, w2b, b2r, wfb);
  k_lc1<<<dim3(16, 169), 256, 0, stream>>>(xB, w1b, b1r, h1b);
  k_lc2<<<dim3(64, 25), 256, 0, stream>>>(h1b, w2b, b2r, h2b);
  k_fc<<<256, 256, 0, stream>>>(h2b, wfb, f1b, f2w, f2b, out);
}

// Round 11
// 118.206 us; speedup vs baseline: 2.3170x; 1.0173x over previous
//
#include <hip/hip_runtime.h>

#define NB 4096

typedef __attribute__((ext_vector_type(8))) short s8v;   // 8 bf16 (4 VGPR)
typedef __attribute__((ext_vector_type(4))) float f4v;   // MFMA acc

// workspace layout (bytes, 16B-aligned)
#define XB_OFF  0u           // 784*4096*2 bf16     =  6,422,528
#define H1B_OFF 6422528u     // 169*4096*16*2 bf16  = 22,151,168
#define H2B_OFF 28573696u    // 25*4096*32*2 bf16   =  6,553,600
#define W2B_OFF 35127296u    // 25*4*8*2*64*8*2     =  1,638,400
#define B2R_OFF 36765696u    // 25*32*4*4           =     12,800
#define W1B_OFF 36778496u    // 169*4*64*8*2        =    692,224
#define B1R_OFF 37470720u    // 169*16*4*4          =     43,264
#define WFB_OFF 37513984u    // 25*8*64*8*2         =    204,800
// end 37,718,784

__device__ __forceinline__ unsigned short f2bf(float f) {
  unsigned int u = __builtin_bit_cast(unsigned int, f);
  u += 0x7fffu + ((u >> 16) & 1u);
  return (unsigned short)(u >> 16);
}

// ---------------------------------------------------------------------------
// prep:
//  [0,1600)      x (4096,784) f32 -> xB (784,4096) bf16 (32c x 64n tiles,
//                LDS restage -> 16B/lane coalesced bf16 stores)
//  [1600,2952)   w1 -> w1b  [pos169][cv4][lane64][t8]  (lc1 B-frags, K=16)
//  [2952,2995)   b1 -> b1r  [pos169][o16][cv4] f32
//  [2995,6195)   w2 -> w2b  [pos25][cv4][s8][ot2][lane64][t8] (lc2 B-frags)
//  6195          b2 -> b2r  [pos25][o32][cv4] f32
//  [6196,6596)   f1w -> wfb [s25][jt8][lane64][t8]  (fc1 B-frags, K-permuted
//                k' = pos*32 + o, i.e. original k = o*25 + s, j = jt*16+lm)
__global__ __launch_bounds__(256) void k_prep(const float* __restrict__ x,
                                              const float* __restrict__ w1,
                                              const float* __restrict__ b1,
                                              const float* __restrict__ w2,
                                              const float* __restrict__ b2,
                                              const float* __restrict__ f1w,
                                              short* __restrict__ xB,
                                              short* __restrict__ w1b,
                                              float* __restrict__ b1r,
                                              short* __restrict__ w2b,
                                              float* __restrict__ b2r,
                                              short* __restrict__ wfb) {
  const int bx = blockIdx.x;
  if (bx < 1600) {
    __shared__ float t2[64][33];
    const int c0 = (bx % 25) * 32;
    const int n0 = (bx / 25) * 64;
    const int tx = threadIdx.x & 31, ty = threadIdx.x >> 5;
    const int c = c0 + tx;
    #pragma unroll
    for (int i = 0; i < 64; i += 8)
      if (c < 784) t2[ty + i][tx] = x[(n0 + ty + i) * 784 + c];
    __syncthreads();
    const int cl = threadIdx.x >> 3;         // 0..31
    const int ns = (threadIdx.x & 7) * 8;    // 0..56
    if (c0 + cl < 784) {
      unsigned short v[8];
      #pragma unroll
      for (int q = 0; q < 8; q++) v[q] = f2bf(t2[ns + q][cl]);
      *reinterpret_cast<s8v*>(&xB[(c0 + cl) * NB + n0 + ns]) =
          *reinterpret_cast<const s8v*>(v);
    }
  } else if (bx < 2952) {
    const int idx = (bx - 1600) * 256 + threadIdx.x;  // 346,112 elems
    const int t = idx & 7;
    const int l = (idx >> 3) & 63;
    const int cv = (idx >> 9) & 3;
    const int pos = idx >> 11;
    const int k = (l >> 4) * 8 + t;
    const int o = l & 15;
    const int i = pos / 13, j = pos % 13;
    const int dy = cv >> 1, dx = cv & 1;
    float v = 0.f;
    if (k < 16) {
      const int py = k >> 2, px = k & 3;
      const int ky = py - dy, kx = px - dx;
      if (ky >= 0 && ky < 3 && kx >= 0 && kx < 3)
        v = w1[(o * 9 + ky * 3 + kx) * 676 + (2 * i + dy) * 26 + 2 * j + dx];
    }
    w1b[idx] = (short)f2bf(v);
  } else if (bx < 2995) {
    const int idx = (bx - 2952) * 256 + threadIdx.x;  // 10,816 elems
    if (idx < 10816) {
      const int cv = idx & 3;
      const int o = (idx >> 2) & 15;
      const int pos = idx >> 6;
      const int i = pos / 13, j = pos % 13;
      b1r[idx] = b1[(o * 26 + 2 * i + (cv >> 1)) * 26 + 2 * j + (cv & 1)];
    }
  } else if (bx < 6195) {
    const int idx = (bx - 2995) * 256 + threadIdx.x;  // 819,200 elems
    const int t = idx & 7;
    const int l = (idx >> 3) & 63;
    const int ot = (idx >> 9) & 1;
    const int s = (idx >> 10) & 7;
    const int cv = (idx >> 13) & 3;
    const int pos = idx >> 15;
    const int k = s * 32 + (l >> 4) * 8 + t;
    const int o = ot * 16 + (l & 15);
    const int w = k >> 4, c = k & 15;
    const int py = w >> 2, px = w & 3;
    const int dy = cv >> 1, dx = cv & 1;
    const int ky = py - dy, kx = px - dx;
    const int I = pos / 5, J = pos % 5;
    float v = 0.f;
    if (ky >= 0 && ky < 3 && kx >= 0 && kx < 3)
      v = w2[((o * 16 + c) * 9 + ky * 3 + kx) * 121 +
             (2 * I + dy) * 11 + (2 * J + dx)];
    w2b[idx] = (short)f2bf(v);
  } else if (bx == 6195) {
    for (int q = threadIdx.x; q < 3200; q += 256) {
      const int pos = q >> 7;
      const int r = q & 127;
      const int o = r >> 2, cv = r & 3;
      const int I = pos / 5, J = pos % 5;
      b2r[q] = b2[o * 121 + (2 * I + (cv >> 1)) * 11 + 2 * J + (cv & 1)];
    }
  } else {
    const int idx = (bx - 6196) * 256 + threadIdx.x;  // 102,400 elems
    const int t = idx & 7;
    const int l = (idx >> 3) & 63;
    const int jt = (idx >> 9) & 7;
    const int s = idx >> 12;
    const int o = (l >> 4) * 8 + t;
    const int j = jt * 16 + (l & 15);
    wfb[idx] = (short)f2bf(f1w[(o * 25 + s) * 128 + j]);
  }
}

// ---------------------------------------------------------------------------
// LC1 via bf16 MFMA 16x16x32 (K=16 real + 16 zero).  xB (784,N) bf16 ->
// h1B (169,N,16c) bf16.  LDS-staged input + write-combined output.
__global__ __launch_bounds__(256, 3) void k_lc1(const short* __restrict__ xB,
                                                const short* __restrict__ w1b,
                                                const float* __restrict__ b1r,
                                                short* __restrict__ h1b) {
  __shared__ short sx[16 * 264 + 16 + 8];       // swizzled [k16][n256]
  __shared__ unsigned short ush[256 * 24];      // [n256 pitch24][o16]
  const int pos = blockIdx.y;
  const int i = pos / 13, j = pos % 13;
  const int tid = threadIdx.x;
  const int l = tid & 63;
  const int wv = tid >> 6;
  const int lm = l & 15, kg = l >> 4;
  const int n0b = blockIdx.x * 256;

  #pragma unroll
  for (int rr = 0; rr < 2; rr++) {
    const int idx = rr * 256 + tid;
    const int row = idx >> 5, seg = idx & 31;
    const int grow = (2 * i + (row >> 2)) * 28 + (2 * j + (row & 3));
    *reinterpret_cast<s8v*>(&sx[row * 264 + ((row >> 3) & 1) * 16 + seg * 8]) =
        *reinterpret_cast<const s8v*>(&xB[grow * NB + n0b + seg * 8]);
  }

  s8v bf[4];
  #pragma unroll
  for (int cv = 0; cv < 4; cv++)
    bf[cv] = *reinterpret_cast<const s8v*>(w1b + ((pos * 4 + cv) * 64 + l) * 8);
  const float4 bias = *reinterpret_cast<const float4*>(b1r + (pos * 16 + lm) * 4);
  __syncthreads();

  f4v acc[4][4];
  #pragma unroll
  for (int a = 0; a < 4; a++)
    #pragma unroll
    for (int cv = 0; cv < 4; cv++) acc[a][cv] = (f4v){0.f, 0.f, 0.f, 0.f};

  #pragma unroll
  for (int a = 0; a < 4; a++) {
    const int nl = wv * 64 + a * 16 + lm;
    s8v av = (s8v){0, 0, 0, 0, 0, 0, 0, 0};
    if (kg < 2) {
      #pragma unroll
      for (int t = 0; t < 8; t++) {
        const int k = kg * 8 + t;
        av[t] = sx[k * 264 + ((k >> 3) & 1) * 16 + nl];
      }
    }
    #pragma unroll
    for (int cv = 0; cv < 4; cv++)
      acc[a][cv] =
          __builtin_amdgcn_mfma_f32_16x16x32_bf16(av, bf[cv], acc[a][cv], 0, 0, 0);
  }

  #pragma unroll
  for (int a = 0; a < 4; a++) {
    #pragma unroll
    for (int reg = 0; reg < 4; reg++) {
      const int nl = wv * 64 + a * 16 + kg * 4 + reg;
      const float v =
          fmaxf(fmaxf(acc[a][0][reg] + bias.x, acc[a][1][reg] + bias.y),
                fmaxf(acc[a][2][reg] + bias.z, acc[a][3][reg] + bias.w));
      ush[nl * 24 + lm] = f2bf(fmaxf(v, 0.f));
    }
  }
  __syncthreads();

  short* dst = h1b + (pos * 4096 + n0b + tid) * 16;
  const unsigned short* src = ush + tid * 24;
  *reinterpret_cast<s8v*>(dst) = *reinterpret_cast<const s8v*>(src);
  *reinterpret_cast<s8v*>(dst + 8) = *reinterpret_cast<const s8v*>(src + 8);
}

// ---------------------------------------------------------------------------
// LC2 via bf16 MFMA 16x16x32.  h1B -> h2b [pos25][n4096][o32] bf16.
// R11: n-tile 128/block (each wave: 4 m-tiles, 128 MFMAs per 32 B-loads) ->
// halves w2b L2 traffic (205->102 MB) and per-MFMA VMEM issue pressure.
// grid (32 nt, 25 pos).
__global__ __launch_bounds__(256, 4) void k_lc2(const short* __restrict__ h1b,
                                                const short* __restrict__ w2b,
                                                const float* __restrict__ b2r,
                                                short* __restrict__ h2b) {
  const int pos = blockIdx.y;
  const int I = pos / 5, J = pos % 5;
  const int tid = threadIdx.x;
  const int l = tid & 63;
  const int wave = tid >> 6;
  const int wm = wave >> 1, ot = wave & 1;
  const int nw = blockIdx.x * 128 + wm * 64;   // wave's 64-n base
  const int kg = l >> 4;
  const int lm = l & 15;
  const int c0 = (kg & 1) * 8;
  const int whalf = kg >> 1;

  f4v acc[4][4];
  #pragma unroll
  for (int a = 0; a < 4; a++)
    #pragma unroll
    for (int cv = 0; cv < 4; cv++)
      acc[a][cv] = (f4v){0.f, 0.f, 0.f, 0.f};

  #pragma unroll
  for (int s = 0; s < 8; s++) {
    const int wdw = s * 2 + whalf;
    const int py = wdw >> 2, px = wdw & 3;
    const int p = (2 * I + py) * 13 + (2 * J + px);
    const int abase = (p * 4096 + nw + lm) * 16 + c0;
    s8v av[4];
    #pragma unroll
    for (int a = 0; a < 4; a++)
      av[a] = *reinterpret_cast<const s8v*>(h1b + abase + a * 256);
    #pragma unroll
    for (int cv = 0; cv < 4; cv++) {
      const s8v bf = *reinterpret_cast<const s8v*>(
          w2b + ((((pos * 4 + cv) * 8 + s) * 2 + ot) * 64 + l) * 8);
      #pragma unroll
      for (int a = 0; a < 4; a++)
        acc[a][cv] =
            __builtin_amdgcn_mfma_f32_16x16x32_bf16(av[a], bf, acc[a][cv], 0, 0, 0);
    }
  }

  const int o = ot * 16 + lm;
  const float4 bias = *reinterpret_cast<const float4*>(b2r + (pos * 32 + o) * 4);
  #pragma unroll
  for (int a = 0; a < 4; a++) {
    const int nb = nw + a * 16 + kg * 4;
    #pragma unroll
    for (int reg = 0; reg < 4; reg++) {
      const float v =
          fmaxf(fmaxf(acc[a][0][reg] + bias.x, acc[a][1][reg] + bias.y),
                fmaxf(acc[a][2][reg] + bias.z, acc[a][3][reg] + bias.w));
      h2b[(pos * 4096 + nb + reg) * 32 + o] = (short)f2bf(fmaxf(v, 0.f));
    }
  }
}

// ---------------------------------------------------------------------------
// fused FC1(relu)+FC2 via bf16 MFMA.  h2b (K'-permuted) -> out (N,10).
// grid 256 (n-tile 16), block 256 = 4 waves; wave w covers j-tiles {2w,2w+1}.
__global__ __launch_bounds__(256) void k_fc(const short* __restrict__ h2b,
                                            const short* __restrict__ wfb,
                                            const float* __restrict__ f1b,
                                            const float* __restrict__ f2w,
                                            const float* __restrict__ f2b,
                                            float* __restrict__ out) {
  __shared__ float sh3[128 * 17];   // [j128][n16 pad17]
  __shared__ float swf2[128 * 12];  // fc2 weights, 12-padded
  __shared__ float sb1[128];
  const int tid = threadIdx.x;
  const int l = tid & 63;
  const int w = tid >> 6;
  const int lm = l & 15, kg = l >> 4;
  const int n0 = blockIdx.x * 16;
  const int jt0 = w * 2;

  for (int idx = tid; idx < 1536; idx += 256) {
    const int kk = idx / 12, f = idx % 12;
    swf2[idx] = (f < 10) ? f2w[kk * 10 + f] : 0.f;
  }
  if (tid < 128) sb1[tid] = f1b[tid];

  f4v acc0 = (f4v){0.f, 0.f, 0.f, 0.f};
  f4v acc1 = (f4v){0.f, 0.f, 0.f, 0.f};

  #pragma unroll
  for (int s = 0; s < 25; s++) {
    const s8v av = *reinterpret_cast<const s8v*>(
        h2b + (s * 4096 + n0 + lm) * 32 + kg * 8);
    const s8v b0 = *reinterpret_cast<const s8v*>(
        wfb + ((s * 8 + jt0) * 64 + l) * 8);
    const s8v b1v = *reinterpret_cast<const s8v*>(
        wfb + ((s * 8 + jt0 + 1) * 64 + l) * 8);
    acc0 = __builtin_amdgcn_mfma_f32_16x16x32_bf16(av, b0, acc0, 0, 0, 0);
    acc1 = __builtin_amdgcn_mfma_f32_16x16x32_bf16(av, b1v, acc1, 0, 0, 0);
  }
  __syncthreads();

  #pragma unroll
  for (int q = 0; q < 2; q++) {
    const f4v a = q ? acc1 : acc0;
    const int j = (jt0 + q) * 16 + lm;
    #pragma unroll
    for (int reg = 0; reg < 4; reg++)
      sh3[j * 17 + kg * 4 + reg] = fmaxf(a[reg] + sb1[j], 0.f);
  }
  __syncthreads();

  if (tid < 160) {
    const int oo = tid >> 4, nn = tid & 15;
    float s = f2b[oo];
    for (int j = 0; j < 128; j++)
      s += sh3[j * 17 + nn] * swf2[j * 12 + oo];
    out[(n0 + nn) * 10 + oo] = s;
  }
}

// ---------------------------------------------------------------------------
extern "C" void kernel_launch(void* const* d_in, const int* in_sizes, int n_in,
                              void* d_out, int out_size, void* d_ws,
                              size_t ws_size, hipStream_t stream) {
  const float* x   = (const float*)d_in[0];
  const float* w1  = (const float*)d_in[1];
  const float* b1  = (const float*)d_in[2];
  const float* w2  = (const float*)d_in[3];
  const float* b2  = (const float*)d_in[4];
  const float* f1w = (const float*)d_in[5];
  const float* f1b = (const float*)d_in[6];
  const float* f2w = (const float*)d_in[7];
  const float* f2b = (const float*)d_in[8];
  float* out = (float*)d_out;
  char* ws = (char*)d_ws;
  short* xB  = (short*)(ws + XB_OFF);
  short* h1b = (short*)(ws + H1B_OFF);
  short* h2b = (short*)(ws + H2B_OFF);
  short* w2b = (short*)(ws + W2B_OFF);
  float* b2r = (float*)(ws + B2R_OFF);
  short* w1b = (short*)(ws + W1B_OFF);
  float* b1r = (float*)(ws + B1R_OFF);
  short* wfb = (short*)(ws + WFB_OFF);

  k_prep<<<6596, 256, 0, stream>>>(x, w1, b1, w2, b2, f1w,
                                   xB, w1b, b1r, w2b, b2r, wfb);
  k_lc1<<<dim3(16, 169), 256, 0, stream>>>(xB, w1b, b1r, h1b);
  k_lc2<<<dim3(32, 25), 256, 0, stream>>>(h1b, w2b, b2r, h2b);
  k_fc<<<256, 256, 0, stream>>>(h2b, wfb, f1b, f2w, f2b, out);
}

// Round 12
// 116.918 us; speedup vs baseline: 2.3425x; 1.0110x over previous
//
#include <hip/hip_runtime.h>

#define NB 4096

typedef __attribute__((ext_vector_type(8))) short s8v;   // 8 bf16 (4 VGPR)
typedef __attribute__((ext_vector_type(4))) float f4v;   // MFMA acc

// workspace layout (bytes, 16B-aligned)
#define XB_OFF  0u           // 784*4096*2 bf16     =  6,422,528
#define H1B_OFF 6422528u     // 169*4096*16*2 bf16  = 22,151,168
#define H2B_OFF 28573696u    // 25*4096*32*2 bf16   =  6,553,600
#define W2B_OFF 35127296u    // 25*4*8*2*64*8*2     =  1,638,400
#define B2R_OFF 36765696u    // 25*32*4*4           =     12,800
#define W1B_OFF 36778496u    // 169*4*64*8*2        =    692,224
#define B1R_OFF 37470720u    // 169*16*4*4          =     43,264
#define WFB_OFF 37513984u    // 25*8*64*8*2         =    204,800
// end 37,718,784

__device__ __forceinline__ unsigned short f2bf(float f) {
  unsigned int u = __builtin_bit_cast(unsigned int, f);
  u += 0x7fffu + ((u >> 16) & 1u);
  return (unsigned short)(u >> 16);
}

// ---------------------------------------------------------------------------
// prep (R12: weight gathers vectorized -- 8 contiguous bf16 per thread, one
// s8v store; grid 6596 -> 2263 blocks):
//  [0,1600)      x -> xB (784,4096) bf16 (32c x 64n tiles, LDS restage)
//  [1600,1769)   w1 -> w1b  [pos169][cv4][lane64][t8]  (lc1 B-frags)
//  [1769,1812)   b1 -> b1r  [pos169][o16][cv4] f32
//  [1812,2212)   w2 -> w2b  [pos25][cv4][s8][ot2][lane64][t8] (lc2 B-frags)
//  2212          b2 -> b2r  [pos25][o32][cv4] f32
//  [2213,2263)   f1w -> wfb [s25][jt8][lane64][t8]  (fc1 B-frags, k=o*25+s)
__global__ __launch_bounds__(256) void k_prep(const float* __restrict__ x,
                                              const float* __restrict__ w1,
                                              const float* __restrict__ b1,
                                              const float* __restrict__ w2,
                                              const float* __restrict__ b2,
                                              const float* __restrict__ f1w,
                                              short* __restrict__ xB,
                                              short* __restrict__ w1b,
                                              float* __restrict__ b1r,
                                              short* __restrict__ w2b,
                                              float* __restrict__ b2r,
                                              short* __restrict__ wfb) {
  const int bx = blockIdx.x;
  if (bx < 1600) {
    __shared__ float t2[64][33];
    const int c0 = (bx % 25) * 32;
    const int n0 = (bx / 25) * 64;
    const int tx = threadIdx.x & 31, ty = threadIdx.x >> 5;
    const int c = c0 + tx;
    #pragma unroll
    for (int i = 0; i < 64; i += 8)
      if (c < 784) t2[ty + i][tx] = x[(n0 + ty + i) * 784 + c];
    __syncthreads();
    const int cl = threadIdx.x >> 3;
    const int ns = (threadIdx.x & 7) * 8;
    if (c0 + cl < 784) {
      unsigned short v[8];
      #pragma unroll
      for (int q = 0; q < 8; q++) v[q] = f2bf(t2[ns + q][cl]);
      *reinterpret_cast<s8v*>(&xB[(c0 + cl) * NB + n0 + ns]) =
          *reinterpret_cast<const s8v*>(v);
    }
  } else if (bx < 1769) {
    const int q = (bx - 1600) * 256 + threadIdx.x;  // 43,264 groups of 8
    const int l = q & 63;
    const int cv = (q >> 6) & 3;
    const int pos = q >> 8;
    const int o = l & 15;
    const int i = pos / 13, j = pos % 13;
    const int dy = cv >> 1, dx = cv & 1;
    unsigned short v[8];
    #pragma unroll
    for (int t = 0; t < 8; t++) {
      const int k = (l >> 4) * 8 + t;
      float f = 0.f;
      if (k < 16) {
        const int py = k >> 2, px = k & 3;
        const int ky = py - dy, kx = px - dx;
        if (ky >= 0 && ky < 3 && kx >= 0 && kx < 3)
          f = w1[(o * 9 + ky * 3 + kx) * 676 + (2 * i + dy) * 26 + 2 * j + dx];
      }
      v[t] = f2bf(f);
    }
    *reinterpret_cast<s8v*>(&w1b[q * 8]) = *reinterpret_cast<const s8v*>(v);
  } else if (bx < 1812) {
    const int idx = (bx - 1769) * 256 + threadIdx.x;  // 10,816 elems
    if (idx < 10816) {
      const int cv = idx & 3;
      const int o = (idx >> 2) & 15;
      const int pos = idx >> 6;
      const int i = pos / 13, j = pos % 13;
      b1r[idx] = b1[(o * 26 + 2 * i + (cv >> 1)) * 26 + 2 * j + (cv & 1)];
    }
  } else if (bx < 2212) {
    const int q = (bx - 1812) * 256 + threadIdx.x;  // 102,400 groups of 8
    const int l = q & 63;
    const int ot = (q >> 6) & 1;
    const int s = (q >> 7) & 7;
    const int cv = (q >> 10) & 3;
    const int pos = q >> 12;
    const int o = ot * 16 + (l & 15);
    const int dy = cv >> 1, dx = cv & 1;
    const int I = pos / 5, J = pos % 5;
    unsigned short v[8];
    #pragma unroll
    for (int t = 0; t < 8; t++) {
      const int k = s * 32 + (l >> 4) * 8 + t;
      const int w = k >> 4, c = k & 15;
      const int py = w >> 2, px = w & 3;
      const int ky = py - dy, kx = px - dx;
      float f = 0.f;
      if (ky >= 0 && ky < 3 && kx >= 0 && kx < 3)
        f = w2[((o * 16 + c) * 9 + ky * 3 + kx) * 121 +
               (2 * I + dy) * 11 + (2 * J + dx)];
      v[t] = f2bf(f);
    }
    *reinterpret_cast<s8v*>(&w2b[q * 8]) = *reinterpret_cast<const s8v*>(v);
  } else if (bx == 2212) {
    for (int q = threadIdx.x; q < 3200; q += 256) {
      const int pos = q >> 7;
      const int r = q & 127;
      const int o = r >> 2, cv = r & 3;
      const int I = pos / 5, J = pos % 5;
      b2r[q] = b2[o * 121 + (2 * I + (cv >> 1)) * 11 + 2 * J + (cv & 1)];
    }
  } else {
    const int q = (bx - 2213) * 256 + threadIdx.x;  // 12,800 groups of 8
    const int l = q & 63;
    const int jt = (q >> 6) & 7;
    const int s = q >> 9;
    const int j = jt * 16 + (l & 15);
    unsigned short v[8];
    #pragma unroll
    for (int t = 0; t < 8; t++) {
      const int o = (l >> 4) * 8 + t;
      v[t] = f2bf(f1w[(o * 25 + s) * 128 + j]);
    }
    *reinterpret_cast<s8v*>(&wfb[q * 8]) = *reinterpret_cast<const s8v*>(v);
  }
}

// ---------------------------------------------------------------------------
// LC1 via bf16 MFMA 16x16x32 (K=16 real + 16 zero).  xB (784,N) bf16 ->
// h1B (169,N,16c) bf16.  LDS-staged input + write-combined output.
__global__ __launch_bounds__(256, 3) void k_lc1(const short* __restrict__ xB,
                                                const short* __restrict__ w1b,
                                                const float* __restrict__ b1r,
                                                short* __restrict__ h1b) {
  __shared__ short sx[16 * 264 + 16 + 8];       // swizzled [k16][n256]
  __shared__ unsigned short ush[256 * 24];      // [n256 pitch24][o16]
  const int pos = blockIdx.y;
  const int i = pos / 13, j = pos % 13;
  const int tid = threadIdx.x;
  const int l = tid & 63;
  const int wv = tid >> 6;
  const int lm = l & 15, kg = l >> 4;
  const int n0b = blockIdx.x * 256;

  #pragma unroll
  for (int rr = 0; rr < 2; rr++) {
    const int idx = rr * 256 + tid;
    const int row = idx >> 5, seg = idx & 31;
    const int grow = (2 * i + (row >> 2)) * 28 + (2 * j + (row & 3));
    *reinterpret_cast<s8v*>(&sx[row * 264 + ((row >> 3) & 1) * 16 + seg * 8]) =
        *reinterpret_cast<const s8v*>(&xB[grow * NB + n0b + seg * 8]);
  }

  s8v bf[4];
  #pragma unroll
  for (int cv = 0; cv < 4; cv++)
    bf[cv] = *reinterpret_cast<const s8v*>(w1b + ((pos * 4 + cv) * 64 + l) * 8);
  const float4 bias = *reinterpret_cast<const float4*>(b1r + (pos * 16 + lm) * 4);
  __syncthreads();

  f4v acc[4][4];
  #pragma unroll
  for (int a = 0; a < 4; a++)
    #pragma unroll
    for (int cv = 0; cv < 4; cv++) acc[a][cv] = (f4v){0.f, 0.f, 0.f, 0.f};

  #pragma unroll
  for (int a = 0; a < 4; a++) {
    const int nl = wv * 64 + a * 16 + lm;
    s8v av = (s8v){0, 0, 0, 0, 0, 0, 0, 0};
    if (kg < 2) {
      #pragma unroll
      for (int t = 0; t < 8; t++) {
        const int k = kg * 8 + t;
        av[t] = sx[k * 264 + ((k >> 3) & 1) * 16 + nl];
      }
    }
    #pragma unroll
    for (int cv = 0; cv < 4; cv++)
      acc[a][cv] =
          __builtin_amdgcn_mfma_f32_16x16x32_bf16(av, bf[cv], acc[a][cv], 0, 0, 0);
  }

  #pragma unroll
  for (int a = 0; a < 4; a++) {
    #pragma unroll
    for (int reg = 0; reg < 4; reg++) {
      const int nl = wv * 64 + a * 16 + kg * 4 + reg;
      const float v =
          fmaxf(fmaxf(acc[a][0][reg] + bias.x, acc[a][1][reg] + bias.y),
                fmaxf(acc[a][2][reg] + bias.z, acc[a][3][reg] + bias.w));
      ush[nl * 24 + lm] = f2bf(fmaxf(v, 0.f));
    }
  }
  __syncthreads();

  short* dst = h1b + (pos * 4096 + n0b + tid) * 16;
  const unsigned short* src = ush + tid * 24;
  *reinterpret_cast<s8v*>(dst) = *reinterpret_cast<const s8v*>(src);
  *reinterpret_cast<s8v*>(dst + 8) = *reinterpret_cast<const s8v*>(src + 8);
}

// ---------------------------------------------------------------------------
// LC2 via bf16 MFMA 16x16x32.  h1B -> h2b [pos25][n4096][o32] bf16.
// R12: full 64KB pos B-slab staged in LDS once (coalesced, one barrier,
// conflict-free b128 readback) -> per-block issued VMEM 256->192 KB; the
// wm-duplicated B reads (102 MB issued chip-wide for 1.6 MB unique) vanish.
// LDS 64KB -> 2 blocks/CU.  grid (32 nt of 128, 25 pos).
__global__ __launch_bounds__(256, 2) void k_lc2(const short* __restrict__ h1b,
                                                const short* __restrict__ w2b,
                                                const float* __restrict__ b2r,
                                                short* __restrict__ h2b) {
  __shared__ short sb[32768];  // [cv4][s8][ot2][lane64][t8] = 64 KB
  const int pos = blockIdx.y;
  const int I = pos / 5, J = pos % 5;
  const int tid = threadIdx.x;
  const int l = tid & 63;
  const int wave = tid >> 6;
  const int wm = wave >> 1, ot = wave & 1;
  const int nw = blockIdx.x * 128 + wm * 64;   // wave's 64-n base
  const int kg = l >> 4;
  const int lm = l & 15;
  const int c0 = (kg & 1) * 8;
  const int whalf = kg >> 1;

  // stage the pos's full B slab: 16 coalesced s8v per thread
  const short* wsrc = w2b + pos * 32768;
  #pragma unroll
  for (int r = 0; r < 16; r++) {
    const int idx = r * 256 + tid;
    *reinterpret_cast<s8v*>(&sb[idx * 8]) =
        *reinterpret_cast<const s8v*>(&wsrc[idx * 8]);
  }
  __syncthreads();

  f4v acc[4][4];
  #pragma unroll
  for (int a = 0; a < 4; a++)
    #pragma unroll
    for (int cv = 0; cv < 4; cv++)
      acc[a][cv] = (f4v){0.f, 0.f, 0.f, 0.f};

  #pragma unroll
  for (int s = 0; s < 8; s++) {
    const int wdw = s * 2 + whalf;
    const int py = wdw >> 2, px = wdw & 3;
    const int p = (2 * I + py) * 13 + (2 * J + px);
    const int abase = (p * 4096 + nw + lm) * 16 + c0;
    s8v av[4];
    #pragma unroll
    for (int a = 0; a < 4; a++)
      av[a] = *reinterpret_cast<const s8v*>(h1b + abase + a * 256);
    #pragma unroll
    for (int cv = 0; cv < 4; cv++) {
      const s8v bf = *reinterpret_cast<const s8v*>(
          &sb[(((cv * 8 + s) * 2 + ot) * 64 + l) * 8]);
      #pragma unroll
      for (int a = 0; a < 4; a++)
        acc[a][cv] =
            __builtin_amdgcn_mfma_f32_16x16x32_bf16(av[a], bf, acc[a][cv], 0, 0, 0);
    }
  }

  const int o = ot * 16 + lm;
  const float4 bias = *reinterpret_cast<const float4*>(b2r + (pos * 32 + o) * 4);
  #pragma unroll
  for (int a = 0; a < 4; a++) {
    const int nb = nw + a * 16 + kg * 4;
    #pragma unroll
    for (int reg = 0; reg < 4; reg++) {
      const float v =
          fmaxf(fmaxf(acc[a][0][reg] + bias.x, acc[a][1][reg] + bias.y),
                fmaxf(acc[a][2][reg] + bias.z, acc[a][3][reg] + bias.w));
      h2b[(pos * 4096 + nb + reg) * 32 + o] = (short)f2bf(fmaxf(v, 0.f));
    }
  }
}

// ---------------------------------------------------------------------------
// fused FC1(relu)+FC2 via bf16 MFMA.  h2b (K'-permuted) -> out (N,10).
// grid 256 (n-tile 16), block 256 = 4 waves; wave w covers j-tiles {2w,2w+1}.
__global__ __launch_bounds__(256) void k_fc(const short* __restrict__ h2b,
                                            const short* __restrict__ wfb,
                                            const float* __restrict__ f1b,
                                            const float* __restrict__ f2w,
                                            const float* __restrict__ f2b,
                                            float* __restrict__ out) {
  __shared__ float sh3[128 * 17];   // [j128][n16 pad17]
  __shared__ float swf2[128 * 12];  // fc2 weights, 12-padded
  __shared__ float sb1[128];
  const int tid = threadIdx.x;
  const int l = tid & 63;
  const int w = tid >> 6;
  const int lm = l & 15, kg = l >> 4;
  const int n0 = blockIdx.x * 16;
  const int jt0 = w * 2;

  for (int idx = tid; idx < 1536; idx += 256) {
    const int kk = idx / 12, f = idx % 12;
    swf2[idx] = (f < 10) ? f2w[kk * 10 + f] : 0.f;
  }
  if (tid < 128) sb1[tid] = f1b[tid];

  f4v acc0 = (f4v){0.f, 0.f, 0.f, 0.f};
  f4v acc1 = (f4v){0.f, 0.f, 0.f, 0.f};

  #pragma unroll
  for (int s = 0; s < 25; s++) {
    const s8v av = *reinterpret_cast<const s8v*>(
        h2b + (s * 4096 + n0 + lm) * 32 + kg * 8);
    const s8v b0 = *reinterpret_cast<const s8v*>(
        wfb + ((s * 8 + jt0) * 64 + l) * 8);
    const s8v b1v = *reinterpret_cast<const s8v*>(
        wfb + ((s * 8 + jt0 + 1) * 64 + l) * 8);
    acc0 = __builtin_amdgcn_mfma_f32_16x16x32_bf16(av, b0, acc0, 0, 0, 0);
    acc1 = __builtin_amdgcn_mfma_f32_16x16x32_bf16(av, b1v, acc1, 0, 0, 0);
  }
  __syncthreads();

  #pragma unroll
  for (int q = 0; q < 2; q++) {
    const f4v a = q ? acc1 : acc0;
    const int j = (jt0 + q) * 16 + lm;
    #pragma unroll
    for (int reg = 0; reg < 4; reg++)
      sh3[j * 17 + kg * 4 + reg] = fmaxf(a[reg] + sb1[j], 0.f);
  }
  __syncthreads();

  if (tid < 160) {
    const int oo = tid >> 4, nn = tid & 15;
    float s = f2b[oo];
    for (int j = 0; j < 128; j++)
      s += sh3[j * 17 + nn] * swf2[j * 12 + oo];
    out[(n0 + nn) * 10 + oo] = s;
  }
}

// ---------------------------------------------------------------------------
extern "C" void kernel_launch(void* const* d_in, const int* in_sizes, int n_in,
                              void* d_out, int out_size, void* d_ws,
                              size_t ws_size, hipStream_t stream) {
  const float* x   = (const float*)d_in[0];
  const float* w1  = (const float*)d_in[1];
  const float* b1  = (const float*)d_in[2];
  const float* w2  = (const float*)d_in[3];
  const float* b2  = (const float*)d_in[4];
  const float* f1w = (const float*)d_in[5];
  const float* f1b = (const float*)d_in[6];
  const float* f2w = (const float*)d_in[7];
  const float* f2b = (const float*)d_in[8];
  float* out = (float*)d_out;
  char* ws = (char*)d_ws;
  short* xB  = (short*)(ws + XB_OFF);
  short* h1b = (short*)(ws + H1B_OFF);
  short* h2b = (short*)(ws + H2B_OFF);
  short* w2b = (short*)(ws + W2B_OFF);
  float* b2r = (float*)(ws + B2R_OFF);
  short* w1b = (short*)(ws + W1B_OFF);
  float* b1r = (float*)(ws + B1R_OFF);
  short* wfb = (short*)(ws + WFB_OFF);

  k_prep<<<2263, 256, 0, stream>>>(x, w1, b1, w2, b2, f1w,
                                   xB, w1b, b1r, w2b, b2r, wfb);
  k_lc1<<<dim3(16, 169), 256, 0, stream>>>(xB, w1b, b1r, h1b);
  k_lc2<<<dim3(32, 25), 256, 0, stream>>>(h1b, w2b, b2r, h2b);
  k_fc<<<256, 256, 0, stream>>>(h2b, wfb, f1b, f2w, f2b, out);
}